// Round 1
// baseline (2928.010 us; speedup 1.0000x reference)
//
#include <hip/hip_runtime.h>
#include <math.h>

#define Bb 64
#define Ss 128
#define BS 8192
#define Ww 16
#define CE 50
#define CH 100
#define EMBD 300
#define HID 256
#define WG 1024
#define XD 400
#define NT 50

typedef unsigned short ushort_t;
typedef unsigned int uint_t;

__device__ __forceinline__ float sigf(float x){ return 1.0f/(1.0f+__expf(-x)); }
__device__ __forceinline__ float tanhfast(float x){
  float e = __expf(-2.0f*fabsf(x));
  float r = (1.0f-e)/(1.0f+e);
  return copysignf(r,x);
}
__device__ __forceinline__ ushort_t f2bf(float f){
  uint_t u = __float_as_uint(f);
  uint_t r = (u + 0x7fffu + ((u>>16)&1u)) >> 16;
  return (ushort_t)r;
}
__device__ __forceinline__ float bflo(uint_t u){ return __uint_as_float(u<<16); }
__device__ __forceinline__ float bfhi(uint_t u){ return __uint_as_float(u & 0xffff0000u); }

// ---------------- Wh f32 -> bf16, packed [(kpair)*256 + j][8] = {k0:g0..g3, k1:g0..g3}
__global__ void k_cvt_wh(const float* __restrict__ whf, const float* __restrict__ whb,
                         ushort_t* __restrict__ pf, ushort_t* __restrict__ pb){
  int i = blockIdx.x*256 + threadIdx.x;
  if (i >= 2*WG*HID) return;
  int which = i >= WG*HID;
  int ii = which ? i - WG*HID : i;
  const float* src = which ? whb : whf;
  ushort_t* dst = which ? pb : pf;
  int kp = ii >> 11, j = (ii>>3)&255, u = ii&7;
  int k = kp*2 + (u>>2), g = u&3;
  dst[ii] = f2bf(src[(g*HID + j)*HID + k]);
}

// ---------------- char BiLSTM: 32 seqs/block, thread=(j hidden, sq seq-half), all 4 gates
__global__ __launch_bounds__(256) void k_char(const int* __restrict__ words, const float* __restrict__ cemb,
    const float* __restrict__ cWiF, const float* __restrict__ cWhF, const float* __restrict__ cbF, float* __restrict__ hfo,
    const float* __restrict__ cWiB, const float* __restrict__ cWhB, const float* __restrict__ cbB, float* __restrict__ hbo)
{
  const int rev = blockIdx.y;
  const float* cWi = rev ? cWiB : cWiF;
  const float* cWh = rev ? cWhB : cWhF;
  const float* cb  = rev ? cbB  : cbF;
  float* hout = rev ? hbo : hfo;

  const int n0 = blockIdx.x * 32;
  const int tid = threadIdx.x;
  const int j = tid & 127;
  const int sq = tid >> 7;           // 0..1 -> seqs sq*16 .. sq*16+15
  const bool act = (j < CH);

  __shared__ float xh[32][152];      // [s][0..49]=x, [s][52..151]=h (52 keeps h 16B-aligned)

  for (int i = tid; i < 32*CH; i += 256) xh[i/CH][52 + (i%CH)] = 0.0f;
  float c[16];
  #pragma unroll
  for (int s=0;s<16;s++) c[s]=0.f;

  float bias0=0.f,bias1=0.f,bias2=0.f,bias3=0.f;
  const float *wi0=nullptr,*wi1=nullptr,*wi2=nullptr,*wi3=nullptr;
  const float *wh0=nullptr,*wh1=nullptr,*wh2=nullptr,*wh3=nullptr;
  if (act){
    bias0 = cb[j]; bias1 = cb[CH+j]; bias2 = cb[2*CH+j]; bias3 = cb[3*CH+j];
    wi0 = cWi + (j)*CE;    wi1 = cWi + (CH+j)*CE;
    wi2 = cWi + (2*CH+j)*CE; wi3 = cWi + (3*CH+j)*CE;
    wh0 = cWh + (j)*CH;    wh1 = cWh + (CH+j)*CH;
    wh2 = cWh + (2*CH+j)*CH; wh3 = cWh + (3*CH+j)*CH;
  }
  __syncthreads();

  for (int t=0;t<Ww;t++){
    int tt = rev ? (Ww-1-t) : t;
    // load x_t for 32 seqs (char_emb gather; row 0 is zeros in the data)
    for (int i = tid; i < 32*CE; i += 256){
      int s = i / CE, e = i - s*CE;
      int w = words[(n0+s)*Ww + tt];
      xh[s][e] = cemb[w*CE + e];
    }
    __syncthreads();

    float acc0[16], acc1[16], acc2[16], acc3[16];
    if (act){
      #pragma unroll
      for (int s=0;s<16;s++){ acc0[s]=bias0; acc1[s]=bias1; acc2[s]=bias2; acc3[s]=bias3; }
      for (int k=0;k<CE;k++){
        float w0=wi0[k], w1=wi1[k], w2=wi2[k], w3=wi3[k];
        #pragma unroll
        for (int s=0;s<16;s++){
          float xv = xh[sq*16+s][k];
          acc0[s]=fmaf(w0,xv,acc0[s]); acc1[s]=fmaf(w1,xv,acc1[s]);
          acc2[s]=fmaf(w2,xv,acc2[s]); acc3[s]=fmaf(w3,xv,acc3[s]);
        }
      }
      for (int k=0;k<CH;k+=4){
        float4 w0 = *(const float4*)(wh0+k);
        float4 w1 = *(const float4*)(wh1+k);
        float4 w2 = *(const float4*)(wh2+k);
        float4 w3 = *(const float4*)(wh3+k);
        #pragma unroll
        for (int s=0;s<16;s++){
          float4 hv = *(const float4*)&xh[sq*16+s][52+k];
          acc0[s] += w0.x*hv.x + w0.y*hv.y + w0.z*hv.z + w0.w*hv.w;
          acc1[s] += w1.x*hv.x + w1.y*hv.y + w1.z*hv.z + w1.w*hv.w;
          acc2[s] += w2.x*hv.x + w2.y*hv.y + w2.z*hv.z + w2.w*hv.w;
          acc3[s] += w3.x*hv.x + w3.y*hv.y + w3.z*hv.z + w3.w*hv.w;
        }
      }
    }
    __syncthreads();   // all h reads done before overwrite
    if (act){
      #pragma unroll
      for (int s=0;s<16;s++){
        float iv = sigf(acc0[s]);
        float fv = sigf(acc1[s]);
        float gv = tanhfast(acc2[s]);
        float ov = sigf(acc3[s]);
        float cn = fmaf(fv, c[s], iv*gv);
        c[s] = cn;
        float hn = ov*tanhfast(cn);
        xh[sq*16+s][52+j] = hn;
        if (t == Ww-1) hout[(n0+sq*16+s)*CH + j] = hn;
      }
    }
    // next iteration's x-load touches disjoint LDS; barrier after load covers h-write visibility
  }
}

// ---------------- x = [word_emb gather | hf+hb]
__global__ void k_build_x(const int* __restrict__ sent, const float* __restrict__ wemb,
                          const float* __restrict__ hf, const float* __restrict__ hb,
                          float* __restrict__ x){
  long i = (long)blockIdx.x*256 + threadIdx.x;
  if (i >= (long)BS*XD) return;
  int n = (int)(i / XD), e = (int)(i - (long)n*XD);
  float v;
  if (e < EMBD) v = wemb[(long)sent[n]*EMBD + e];
  else { int jj = e-EMBD; v = hf[n*CH+jj] + hb[n*CH+jj]; }
  x[i] = v;
}

// ---------------- word input-gate GEMM: gout[8192,1024] = A @ Wi^T + b ; rev folds xr remap
__global__ __launch_bounds__(256) void k_gemm(const float* __restrict__ x, const int* __restrict__ lengths,
    const float* __restrict__ WiF, const float* __restrict__ wbF, float* __restrict__ goutF,
    const float* __restrict__ WiB, const float* __restrict__ wbB, float* __restrict__ goutB)
{
  const int rev = blockIdx.z;
  const float* Wi  = rev ? WiB  : WiF;
  const float* bias= rev ? wbB  : wbF;
  float* gout      = rev ? goutB: goutF;

  const int m0 = blockIdx.x * 128, n0 = blockIdx.y * 128;
  const int b  = m0 >> 7;
  const int L  = lengths[b];

  __shared__ float Al[16][132];
  __shared__ float Bl[16][132];
  const int tid = threadIdx.x;
  const int tx = tid & 15, ty = tid >> 4;
  const int r0 = ty*8, c0 = tx*8;

  float acc[8][8];
  #pragma unroll
  for (int i=0;i<8;i++)
    #pragma unroll
    for (int q=0;q<8;q++) acc[i][q]=0.f;

  float bv[8];
  #pragma unroll
  for (int q=0;q<8;q++) bv[q] = bias[n0+c0+q];

  for (int k0=0;k0<XD;k0+=16){
    #pragma unroll
    for (int u=0;u<2;u++){
      int idx = tid*2+u;              // 0..511
      int r = idx>>2, kq = idx&3;     // r = t within sentence
      bool zz = false; int srcrow;
      if (!rev) srcrow = m0 + r;
      else { if (r < L) srcrow = b*Ss + (L-1-r); else { zz = true; srcrow = b*Ss; } }
      float4 v = make_float4(0.f,0.f,0.f,0.f);
      if (!zz) v = *(const float4*)&x[(long)srcrow*XD + k0 + kq*4];
      Al[kq*4+0][r]=v.x; Al[kq*4+1][r]=v.y; Al[kq*4+2][r]=v.z; Al[kq*4+3][r]=v.w;
    }
    {
      int kk = tid & 15, ng = tid >> 4;
      #pragma unroll
      for (int u=0;u<8;u++){
        int nn = ng*8+u;
        Bl[kk][nn] = Wi[(long)(n0+nn)*XD + k0 + kk];
      }
    }
    __syncthreads();
    #pragma unroll
    for (int kk=0;kk<16;kk++){
      float4 a0 = *(const float4*)&Al[kk][r0];
      float4 a1 = *(const float4*)&Al[kk][r0+4];
      float4 b0 = *(const float4*)&Bl[kk][c0];
      float4 b1 = *(const float4*)&Bl[kk][c0+4];
      float av[8] = {a0.x,a0.y,a0.z,a0.w,a1.x,a1.y,a1.z,a1.w};
      float bw[8] = {b0.x,b0.y,b0.z,b0.w,b1.x,b1.y,b1.z,b1.w};
      #pragma unroll
      for (int i=0;i<8;i++)
        #pragma unroll
        for (int q=0;q<8;q++) acc[i][q] = fmaf(av[i], bw[q], acc[i][q]);
    }
    __syncthreads();
  }
  #pragma unroll
  for (int i=0;i<8;i++){
    int row = m0 + r0 + i;
    float4 o0 = make_float4(acc[i][0]+bv[0], acc[i][1]+bv[1], acc[i][2]+bv[2], acc[i][3]+bv[3]);
    float4 o1 = make_float4(acc[i][4]+bv[4], acc[i][5]+bv[5], acc[i][6]+bv[6], acc[i][7]+bv[7]);
    *(float4*)&gout[(long)row*WG + n0 + c0]     = o0;
    *(float4*)&gout[(long)row*WG + n0 + c0 + 4] = o1;
  }
}

// ---------------- word LSTM recurrence: 1 block per (seq, dir); thread j owns hidden j
__global__ __launch_bounds__(256) void k_word(const float* __restrict__ gWf, const ushort_t* __restrict__ whPf, float* __restrict__ hfw,
                                              const float* __restrict__ gWb, const ushort_t* __restrict__ whPb, float* __restrict__ hrw)
{
  const int rev = blockIdx.y;
  const float* gW = rev ? gWb : gWf;
  const ushort_t* wh = rev ? whPb : whPf;
  float* hout = rev ? hrw : hfw;

  const int b = blockIdx.x;
  const int j = threadIdx.x;
  __shared__ float h[HID];
  h[j] = 0.f;
  float c = 0.f;
  __syncthreads();

  const ushort_t* wbase = wh + j*8;
  for (int t=0;t<Ss;t++){
    const float* gw = gW + (long)(b*Ss + t)*WG;
    float a0 = gw[j], a1 = gw[HID+j], a2 = gw[2*HID+j], a3 = gw[3*HID+j];
    #pragma unroll 4
    for (int kp=0; kp<128; kp++){
      uint4 wv = *(const uint4*)(wbase + (long)kp*2048);
      float2 hv = *(const float2*)&h[kp*2];
      a0 = fmaf(bflo(wv.x), hv.x, a0); a1 = fmaf(bfhi(wv.x), hv.x, a1);
      a2 = fmaf(bflo(wv.y), hv.x, a2); a3 = fmaf(bfhi(wv.y), hv.x, a3);
      a0 = fmaf(bflo(wv.z), hv.y, a0); a1 = fmaf(bfhi(wv.z), hv.y, a1);
      a2 = fmaf(bflo(wv.w), hv.y, a2); a3 = fmaf(bfhi(wv.w), hv.y, a3);
    }
    float iv = sigf(a0), fv = sigf(a1), gv = tanhfast(a2), ov = sigf(a3);
    c = fmaf(fv, c, iv*gv);
    float hn = ov*tanhfast(c);
    __syncthreads();      // everyone done reading h
    h[j] = hn;
    hout[(long)(b*Ss+t)*HID + j] = hn;
    __syncthreads();
  }
}

// ---------------- emissions: emit = concat(h_fwd, h_bwd)*valid @ We^T + be
__global__ __launch_bounds__(128) void k_emit(const float* __restrict__ hfw, const float* __restrict__ hrw,
    const int* __restrict__ lengths, const float* __restrict__ We, const float* __restrict__ be,
    float* __restrict__ emit)
{
  __shared__ float Wl[NT*516];
  const int b = blockIdx.x, tg = blockIdx.y;
  const int tid = threadIdx.x;
  for (int i = tid; i < NT*512; i += 128)
    Wl[(i>>9)*516 + (i&511)] = We[i];
  __syncthreads();
  const int L = lengths[b];
  const int j = tid & 63;
  const int th = tid >> 6;
  float bej = (j<NT) ? be[j] : 0.f;
  for (int ttq=0; ttq<8; ttq++){
    int t = tg*16 + th*8 + ttq;
    int n = b*Ss + t;
    float acc = bej;
    if (j < NT && t < L){
      const float* hf_ = hfw + (long)n*HID;
      const float* hb_ = hrw + (long)(b*Ss + (L-1-t))*HID;
      const float* wr = Wl + j*516;
      for (int k=0;k<HID;k+=4){
        float4 hv = *(const float4*)(hf_+k);
        float4 wv = *(const float4*)(wr+k);
        acc += hv.x*wv.x + hv.y*wv.y + hv.z*wv.z + hv.w*wv.w;
      }
      for (int k=0;k<HID;k+=4){
        float4 hv = *(const float4*)(hb_+k);
        float4 wv = *(const float4*)(wr+256+k);
        acc += hv.x*wv.x + hv.y*wv.y + hv.z*wv.z + hv.w*wv.w;
      }
    }
    if (j < NT) emit[(long)n*NT + j] = acc;
  }
}

// ---------------- CRF: gold score + exp-domain forward algorithm; out = pred - gold
__global__ __launch_bounds__(64) void k_crf(const float* __restrict__ emit, const int* __restrict__ tags,
    const int* __restrict__ lengths, const float* __restrict__ trans, float* __restrict__ out)
{
  const int b = blockIdx.x;
  const int tid = threadIdx.x;
  __shared__ float Tl[NT*NT];
  __shared__ float A[NT];
  __shared__ float red[64];
  for (int i=tid;i<NT*NT;i+=64) Tl[i] = trans[i];
  __syncthreads();
  const int L = lengths[b];

  // gold
  float gp = 0.f;
  for (int t=tid; t<L; t+=64){
    int tg = tags[b*Ss+t];
    gp += emit[(long)(b*Ss+t)*NT + tg];
    if (t>=1) gp += Tl[tags[b*Ss+t-1]*NT + tg];
  }
  red[tid] = gp; __syncthreads();
  for (int off=32; off; off>>=1){ if (tid<off) red[tid]+=red[tid+off]; __syncthreads(); }
  float gold = red[0];

  // forward algorithm in exp-domain with per-step renorm
  const int j = tid;
  float Ereg[NT];
  if (j < NT){
    #pragma unroll
    for (int i=0;i<NT;i++) Ereg[i] = __expf(Tl[i*NT + j]);
  }
  float a0 = (j<NT) ? emit[(long)(b*Ss)*NT + j] : -1e30f;
  float m = a0;
  #pragma unroll
  for (int off=1; off<64; off<<=1) m = fmaxf(m, __shfl_xor(m, off));
  float logZ = m;
  if (j<NT) A[j] = __expf(a0 - m);
  __syncthreads();

  for (int t=1;t<L;t++){
    float v = 0.f;
    if (j<NT){
      #pragma unroll
      for (int i=0;i<NT;i++) v = fmaf(A[i], Ereg[i], v);
      v *= __expf(emit[(long)(b*Ss+t)*NT + j]);
    }
    float mm = (j<NT) ? v : 0.f;
    #pragma unroll
    for (int off=1; off<64; off<<=1) mm = fmaxf(mm, __shfl_xor(mm, off));
    logZ += __logf(mm);
    float vn = v / mm;
    __syncthreads();
    if (j<NT) A[j] = vn;
    __syncthreads();
  }
  float s = (j<NT) ? A[j] : 0.f;
  #pragma unroll
  for (int off=1; off<64; off<<=1) s += __shfl_xor(s, off);
  float pred = logZ + __logf(s);
  if (tid==0) out[b] = pred - gold;
}

extern "C" void kernel_launch(void* const* d_in, const int* in_sizes, int n_in,
                              void* d_out, int out_size, void* d_ws, size_t ws_size,
                              hipStream_t stream){
  const int*   sentences = (const int*)d_in[0];
  const int*   lengths   = (const int*)d_in[1];
  const int*   words     = (const int*)d_in[2];
  const int*   tags      = (const int*)d_in[3];
  const float* char_emb  = (const float*)d_in[4];
  const float* cWi_f = (const float*)d_in[5];
  const float* cWh_f = (const float*)d_in[6];
  const float* cb_f  = (const float*)d_in[7];
  const float* cWi_b = (const float*)d_in[8];
  const float* cWh_b = (const float*)d_in[9];
  const float* cb_b  = (const float*)d_in[10];
  const float* word_emb = (const float*)d_in[11];
  const float* wWi_f = (const float*)d_in[12];
  const float* wWh_f = (const float*)d_in[13];
  const float* wb_f  = (const float*)d_in[14];
  const float* wWi_b = (const float*)d_in[15];
  const float* wWh_b = (const float*)d_in[16];
  const float* wb_b  = (const float*)d_in[17];
  const float* We   = (const float*)d_in[18];
  const float* be   = (const float*)d_in[19];
  const float* trans= (const float*)d_in[20];
  float* out = (float*)d_out;

  float* ws = (float*)d_ws;
  float* hf   = ws;                      // 8192*100
  float* hb   = hf  + 819200;
  float* x    = hb  + 819200;            // 8192*400
  float* gWf  = x   + 3276800;           // 8192*1024
  float* gWb  = gWf + 8388608;
  float* hfw  = gWb + 8388608;           // 8192*256
  float* hrw  = hfw + 2097152;
  float* emit = hrw + 2097152;           // 8192*50
  ushort_t* whPf = (ushort_t*)(emit + 409600);   // 1024*256 bf16
  ushort_t* whPb = whPf + 262144;

  k_cvt_wh<<<dim3(2048), 256, 0, stream>>>(wWh_f, wWh_b, whPf, whPb);
  k_char<<<dim3(256,2), 256, 0, stream>>>(words, char_emb,
      cWi_f, cWh_f, cb_f, hf,
      cWi_b, cWh_b, cb_b, hb);
  k_build_x<<<dim3(12800), 256, 0, stream>>>(sentences, word_emb, hf, hb, x);
  k_gemm<<<dim3(64,8,2), 256, 0, stream>>>(x, lengths, wWi_f, wb_f, gWf, wWi_b, wb_b, gWb);
  k_word<<<dim3(64,2), 256, 0, stream>>>(gWf, whPf, hfw, gWb, whPb, hrw);
  k_emit<<<dim3(64,8), 128, 0, stream>>>(hfw, hrw, lengths, We, be, emit);
  k_crf<<<dim3(64), 64, 0, stream>>>(emit, tags, lengths, trans, out);
}

// Round 2
// 1411.148 us; speedup vs baseline: 2.0749x; 2.0749x over previous
//
#include <hip/hip_runtime.h>
#include <math.h>

#define Bb 64
#define Ss 128
#define BS 8192
#define Ww 16
#define CE 50
#define CH 100
#define EMBD 300
#define HID 256
#define WG 1024
#define XD 400
#define NT 50

typedef unsigned short ushort_t;
typedef unsigned int uint_t;
using bf16x8 = __attribute__((ext_vector_type(8))) short;
using f32x4  = __attribute__((ext_vector_type(4))) float;

__device__ __forceinline__ float sigf(float x){ return 1.0f/(1.0f+__expf(-x)); }
__device__ __forceinline__ float tanhfast(float x){
  float e = __expf(-2.0f*fabsf(x));
  float r = (1.0f-e)/(1.0f+e);
  return copysignf(r,x);
}
__device__ __forceinline__ ushort_t f2bf(float f){
  uint_t u = __float_as_uint(f);
  uint_t r = (u + 0x7fffu + ((u>>16)&1u)) >> 16;
  return (ushort_t)r;
}
__device__ __forceinline__ float bflo(uint_t u){ return __uint_as_float(u<<16); }
__device__ __forceinline__ float bfhi(uint_t u){ return __uint_as_float(u & 0xffff0000u); }

// ---------------- Wh f32 -> bf16, packed [(kpair)*256 + j][8] = {k0:g0..g3, k1:g0..g3}
__global__ void k_cvt_wh(const float* __restrict__ whf, const float* __restrict__ whb,
                         ushort_t* __restrict__ pf, ushort_t* __restrict__ pb){
  int i = blockIdx.x*256 + threadIdx.x;
  if (i >= 2*WG*HID) return;
  int which = i >= WG*HID;
  int ii = which ? i - WG*HID : i;
  const float* src = which ? whb : whf;
  ushort_t* dst = which ? pb : pf;
  int kp = ii >> 11, j = (ii>>3)&255, u = ii&7;
  int k = kp*2 + (u>>2), g = u&3;
  dst[ii] = f2bf(src[(g*HID + j)*HID + k]);
}

// ---------------- char BiLSTM via MFMA: gates-on-M (row m = j*4+gate), seqs-on-N.
// Per block: 32 seqs, one dir. gates[400,32] = W[400,192k] @ xh^T[192k,32] per step.
// Wh in per-wave A-frags (registers); Wi + xh in LDS; x prefetched one step ahead.
__global__ __launch_bounds__(256, 2) void k_char_mfma(const int* __restrict__ words, const float* __restrict__ cemb,
    const float* __restrict__ cWiF, const float* __restrict__ cWhF, const float* __restrict__ cbF, float* __restrict__ hfo,
    const float* __restrict__ cWiB, const float* __restrict__ cWhB, const float* __restrict__ cbB, float* __restrict__ hbo)
{
  const int rev = blockIdx.y;
  const float* cWi = rev ? cWiB : cWiF;
  const float* cWh = rev ? cWhB : cWhF;
  const float* cb  = rev ? cbB  : cbF;
  float* hout = rev ? hbo : hfo;
  const int n0 = blockIdx.x * 32;
  const int tid = threadIdx.x;
  const int lane = tid & 63;
  const int w = tid >> 6;                 // wave 0..3

  // k-space: 0..63 = x (50 real), 64..191 = h (100 real); row stride 200 -> bank step 4
  __shared__ ushort_t xh[32][200];
  __shared__ ushort_t wi_l[400][72];      // [m=j*4+g][k 0..63 (+pad)], stride 72 -> bank step 4
  __shared__ float    bias_l[400];
  __shared__ int      wbuf[32][Ww];

  // ---- prologue ----
  for (int i = tid; i < 32*Ww; i += 256)
    wbuf[i>>4][i&15] = words[(n0 + (i>>4))*Ww + (i&15)];
  for (int i = tid; i < 3200; i += 256) ((uint_t*)xh)[i] = 0u;   // zero all of xh (incl pads)
  for (int r = tid; r < 400; r += 256){
    int j = r >> 2, g = r & 3;
    const float* src = cWi + (g*CH + j)*CE;
    for (int k = 0; k < 72; ++k)
      wi_l[r][k] = (k < CE) ? f2bf(src[k]) : (ushort_t)0;
    bias_l[r] = cb[g*CH + j];
  }

  // Wh A-frags in registers: wave w owns M-tiles tm = w, w+4, ... (<25). 25 tiles cover M=400 exactly.
  bf16x8 whr[7][4];
  #pragma unroll
  for (int ti=0; ti<7; ++ti){
    int tm = w + ti*4;
    #pragma unroll
    for (int kk=0; kk<4; ++kk){
      bf16x8 v;
      #pragma unroll
      for (int e=0;e<8;++e) v[e]=0;
      if (tm < 25){
        int m = tm*16 + (lane & 15);
        int j = m >> 2, g = m & 3;
        const float* src = cWh + (g*CH + j)*CH;
        int kh0 = kk*32 + ((lane>>4)<<3);
        #pragma unroll
        for (int e=0;e<8;++e){
          int kh = kh0 + e;
          if (kh < CH) v[e] = (short)f2bf(src[kh]);
        }
      }
      whr[ti][kk] = v;
    }
  }

  float cst[7][2], hreg[7][2];
  #pragma unroll
  for (int ti=0; ti<7; ++ti){ cst[ti][0]=0.f; cst[ti][1]=0.f; hreg[ti][0]=0.f; hreg[ti][1]=0.f; }

  const int ps = tid >> 3;            // seq 0..31 (x staging ownership)
  const int pk = (tid & 7) * 8;       // k base 0..56
  float xv[8];

  __syncthreads();                    // prologue LDS (wbuf etc.) ready

  {  // prefetch x_0
    int tt = rev ? (Ww-1) : 0;
    int wd = wbuf[ps][tt];
    const float* src = cemb + wd*CE + pk;
    #pragma unroll
    for (int e=0;e<8;++e){ int k = pk+e; xv[e] = (k < CE) ? src[e] : 0.f; }
  }

  #pragma unroll 1
  for (int t=0; t<Ww; ++t){
    __syncthreads();                  // barrier A: everyone done reading xh for step t-1
    if (t){                          // write h_{t-1}
      #pragma unroll
      for (int ti=0; ti<7; ++ti){
        int tm = w + ti*4;
        if (tm < 25){
          int j = tm*4 + (lane>>4);
          #pragma unroll
          for (int nt=0; nt<2; ++nt){
            int s = nt*16 + (lane & 15);
            xh[s][64 + j] = f2bf(hreg[ti][nt]);
          }
        }
      }
    }
    {  // write x_t (from prefetch regs)
      bf16x8 pxv;
      #pragma unroll
      for (int e=0;e<8;++e) pxv[e] = (short)f2bf(xv[e]);
      *((bf16x8*)&xh[ps][pk]) = pxv;
    }
    if (t+1 < Ww){                   // prefetch x_{t+1} (hides under MFMA phase)
      int tt2 = rev ? (Ww-2-t) : (t+1);
      int wd = wbuf[ps][tt2];
      const float* src = cemb + wd*CE + pk;
      #pragma unroll
      for (int e=0;e<8;++e){ int k = pk+e; xv[e] = (k < CE) ? src[e] : 0.f; }
    }
    __syncthreads();                  // barrier B: xh (x_t, h_{t-1}) visible

    // B-frags: xh^T tiles, lane: seq = nt*16+(lane&15), k = kk*32+(lane>>4)*8
    bf16x8 bf[2][6];
    #pragma unroll
    for (int nt=0; nt<2; ++nt){
      int s = nt*16 + (lane & 15);
      #pragma unroll
      for (int kk=0; kk<6; ++kk){
        int k = kk*32 + ((lane>>4)<<3);
        bf[nt][kk] = *((const bf16x8*)&xh[s][k]);
      }
    }
    #pragma unroll
    for (int ti=0; ti<7; ++ti){
      int tm = w + ti*4;
      if (tm < 25){
        int row = tm*16 + (lane & 15);
        int kb = (lane>>4)<<3;
        bf16x8 awi0 = *((const bf16x8*)&wi_l[row][kb]);
        bf16x8 awi1 = *((const bf16x8*)&wi_l[row][32+kb]);
        f32x4 bias_v = *((const f32x4*)&bias_l[tm*16 + ((lane>>4)<<2)]);
        #pragma unroll
        for (int nt=0; nt<2; ++nt){
          f32x4 acc = bias_v;
          acc = __builtin_amdgcn_mfma_f32_16x16x32_bf16(awi0, bf[nt][0], acc, 0,0,0);
          acc = __builtin_amdgcn_mfma_f32_16x16x32_bf16(awi1, bf[nt][1], acc, 0,0,0);
          #pragma unroll
          for (int kk=0; kk<4; ++kk)
            acc = __builtin_amdgcn_mfma_f32_16x16x32_bf16(whr[ti][kk], bf[nt][2+kk], acc, 0,0,0);
          // lane holds gates i,f,g,o (regs 0..3) of hidden j = tm*4+(lane>>4), seq = nt*16+(lane&15)
          float iv = sigf(acc[0]), fv = sigf(acc[1]);
          float gv = tanhfast(acc[2]), ov = sigf(acc[3]);
          float cn = fmaf(fv, cst[ti][nt], iv*gv);
          cst[ti][nt] = cn;
          hreg[ti][nt] = ov * tanhfast(cn);
        }
      }
    }
  }

  // final h -> hout
  #pragma unroll
  for (int ti=0; ti<7; ++ti){
    int tm = w + ti*4;
    if (tm < 25){
      int j = tm*4 + (lane>>4);
      #pragma unroll
      for (int nt=0; nt<2; ++nt){
        int s = nt*16 + (lane & 15);
        hout[(n0 + s)*CH + j] = hreg[ti][nt];
      }
    }
  }
}

// ---------------- x = [word_emb gather | hf+hb]
__global__ void k_build_x(const int* __restrict__ sent, const float* __restrict__ wemb,
                          const float* __restrict__ hf, const float* __restrict__ hb,
                          float* __restrict__ x){
  long i = (long)blockIdx.x*256 + threadIdx.x;
  if (i >= (long)BS*XD) return;
  int n = (int)(i / XD), e = (int)(i - (long)n*XD);
  float v;
  if (e < EMBD) v = wemb[(long)sent[n]*EMBD + e];
  else { int jj = e-EMBD; v = hf[n*CH+jj] + hb[n*CH+jj]; }
  x[i] = v;
}

// ---------------- word input-gate GEMM: gout[8192,1024] = A @ Wi^T + b ; rev folds xr remap
__global__ __launch_bounds__(256) void k_gemm(const float* __restrict__ x, const int* __restrict__ lengths,
    const float* __restrict__ WiF, const float* __restrict__ wbF, float* __restrict__ goutF,
    const float* __restrict__ WiB, const float* __restrict__ wbB, float* __restrict__ goutB)
{
  const int rev = blockIdx.z;
  const float* Wi  = rev ? WiB  : WiF;
  const float* bias= rev ? wbB  : wbF;
  float* gout      = rev ? goutB: goutF;

  const int m0 = blockIdx.x * 128, n0 = blockIdx.y * 128;
  const int b  = m0 >> 7;
  const int L  = lengths[b];

  __shared__ float Al[16][132];
  __shared__ float Bl[16][132];
  const int tid = threadIdx.x;
  const int tx = tid & 15, ty = tid >> 4;
  const int r0 = ty*8, c0 = tx*8;

  float acc[8][8];
  #pragma unroll
  for (int i=0;i<8;i++)
    #pragma unroll
    for (int q=0;q<8;q++) acc[i][q]=0.f;

  float bv[8];
  #pragma unroll
  for (int q=0;q<8;q++) bv[q] = bias[n0+c0+q];

  for (int k0=0;k0<XD;k0+=16){
    #pragma unroll
    for (int u=0;u<2;u++){
      int idx = tid*2+u;              // 0..511
      int r = idx>>2, kq = idx&3;     // r = t within sentence
      bool zz = false; int srcrow;
      if (!rev) srcrow = m0 + r;
      else { if (r < L) srcrow = b*Ss + (L-1-r); else { zz = true; srcrow = b*Ss; } }
      float4 v = make_float4(0.f,0.f,0.f,0.f);
      if (!zz) v = *(const float4*)&x[(long)srcrow*XD + k0 + kq*4];
      Al[kq*4+0][r]=v.x; Al[kq*4+1][r]=v.y; Al[kq*4+2][r]=v.z; Al[kq*4+3][r]=v.w;
    }
    {
      int kk = tid & 15, ng = tid >> 4;
      #pragma unroll
      for (int u=0;u<8;u++){
        int nn = ng*8+u;
        Bl[kk][nn] = Wi[(long)(n0+nn)*XD + k0 + kk];
      }
    }
    __syncthreads();
    #pragma unroll
    for (int kk=0;kk<16;kk++){
      float4 a0 = *(const float4*)&Al[kk][r0];
      float4 a1 = *(const float4*)&Al[kk][r0+4];
      float4 b0 = *(const float4*)&Bl[kk][c0];
      float4 b1 = *(const float4*)&Bl[kk][c0+4];
      float av[8] = {a0.x,a0.y,a0.z,a0.w,a1.x,a1.y,a1.z,a1.w};
      float bw[8] = {b0.x,b0.y,b0.z,b0.w,b1.x,b1.y,b1.z,b1.w};
      #pragma unroll
      for (int i=0;i<8;i++)
        #pragma unroll
        for (int q=0;q<8;q++) acc[i][q] = fmaf(av[i], bw[q], acc[i][q]);
    }
    __syncthreads();
  }
  #pragma unroll
  for (int i=0;i<8;i++){
    int row = m0 + r0 + i;
    float4 o0 = make_float4(acc[i][0]+bv[0], acc[i][1]+bv[1], acc[i][2]+bv[2], acc[i][3]+bv[3]);
    float4 o1 = make_float4(acc[i][4]+bv[4], acc[i][5]+bv[5], acc[i][6]+bv[6], acc[i][7]+bv[7]);
    *(float4*)&gout[(long)row*WG + n0 + c0]     = o0;
    *(float4*)&gout[(long)row*WG + n0 + c0 + 4] = o1;
  }
}

// ---------------- word LSTM recurrence: 1 block per (seq, dir); thread j owns hidden j
__global__ __launch_bounds__(256) void k_word(const float* __restrict__ gWf, const ushort_t* __restrict__ whPf, float* __restrict__ hfw,
                                              const float* __restrict__ gWb, const ushort_t* __restrict__ whPb, float* __restrict__ hrw)
{
  const int rev = blockIdx.y;
  const float* gW = rev ? gWb : gWf;
  const ushort_t* wh = rev ? whPb : whPf;
  float* hout = rev ? hrw : hfw;

  const int b = blockIdx.x;
  const int j = threadIdx.x;
  __shared__ float h[HID];
  h[j] = 0.f;
  float c = 0.f;
  __syncthreads();

  const ushort_t* wbase = wh + j*8;
  for (int t=0;t<Ss;t++){
    const float* gw = gW + (long)(b*Ss + t)*WG;
    float a0 = gw[j], a1 = gw[HID+j], a2 = gw[2*HID+j], a3 = gw[3*HID+j];
    #pragma unroll 4
    for (int kp=0; kp<128; kp++){
      uint4 wv = *(const uint4*)(wbase + (long)kp*2048);
      float2 hv = *(const float2*)&h[kp*2];
      a0 = fmaf(bflo(wv.x), hv.x, a0); a1 = fmaf(bfhi(wv.x), hv.x, a1);
      a2 = fmaf(bflo(wv.y), hv.x, a2); a3 = fmaf(bfhi(wv.y), hv.x, a3);
      a0 = fmaf(bflo(wv.z), hv.y, a0); a1 = fmaf(bfhi(wv.z), hv.y, a1);
      a2 = fmaf(bflo(wv.w), hv.y, a2); a3 = fmaf(bfhi(wv.w), hv.y, a3);
    }
    float iv = sigf(a0), fv = sigf(a1), gv = tanhfast(a2), ov = sigf(a3);
    c = fmaf(fv, c, iv*gv);
    float hn = ov*tanhfast(c);
    __syncthreads();      // everyone done reading h
    h[j] = hn;
    hout[(long)(b*Ss+t)*HID + j] = hn;
    __syncthreads();
  }
}

// ---------------- emissions: emit = concat(h_fwd, h_bwd)*valid @ We^T + be
__global__ __launch_bounds__(128) void k_emit(const float* __restrict__ hfw, const float* __restrict__ hrw,
    const int* __restrict__ lengths, const float* __restrict__ We, const float* __restrict__ be,
    float* __restrict__ emit)
{
  __shared__ float Wl[NT*516];
  const int b = blockIdx.x, tg = blockIdx.y;
  const int tid = threadIdx.x;
  for (int i = tid; i < NT*512; i += 128)
    Wl[(i>>9)*516 + (i&511)] = We[i];
  __syncthreads();
  const int L = lengths[b];
  const int j = tid & 63;
  const int th = tid >> 6;
  float bej = (j<NT) ? be[j] : 0.f;
  for (int ttq=0; ttq<8; ttq++){
    int t = tg*16 + th*8 + ttq;
    int n = b*Ss + t;
    float acc = bej;
    if (j < NT && t < L){
      const float* hf_ = hfw + (long)n*HID;
      const float* hb_ = hrw + (long)(b*Ss + (L-1-t))*HID;
      const float* wr = Wl + j*516;
      for (int k=0;k<HID;k+=4){
        float4 hv = *(const float4*)(hf_+k);
        float4 wv = *(const float4*)(wr+k);
        acc += hv.x*wv.x + hv.y*wv.y + hv.z*wv.z + hv.w*wv.w;
      }
      for (int k=0;k<HID;k+=4){
        float4 hv = *(const float4*)(hb_+k);
        float4 wv = *(const float4*)(wr+256+k);
        acc += hv.x*wv.x + hv.y*wv.y + hv.z*wv.z + hv.w*wv.w;
      }
    }
    if (j < NT) emit[(long)n*NT + j] = acc;
  }
}

// ---------------- CRF: gold score + exp-domain forward algorithm; out = pred - gold
__global__ __launch_bounds__(64) void k_crf(const float* __restrict__ emit, const int* __restrict__ tags,
    const int* __restrict__ lengths, const float* __restrict__ trans, float* __restrict__ out)
{
  const int b = blockIdx.x;
  const int tid = threadIdx.x;
  __shared__ float Tl[NT*NT];
  __shared__ float A[NT];
  __shared__ float red[64];
  for (int i=tid;i<NT*NT;i+=64) Tl[i] = trans[i];
  __syncthreads();
  const int L = lengths[b];

  // gold
  float gp = 0.f;
  for (int t=tid; t<L; t+=64){
    int tg = tags[b*Ss+t];
    gp += emit[(long)(b*Ss+t)*NT + tg];
    if (t>=1) gp += Tl[tags[b*Ss+t-1]*NT + tg];
  }
  red[tid] = gp; __syncthreads();
  for (int off=32; off; off>>=1){ if (tid<off) red[tid]+=red[tid+off]; __syncthreads(); }
  float gold = red[0];

  // forward algorithm in exp-domain with per-step renorm
  const int j = tid;
  float Ereg[NT];
  if (j < NT){
    #pragma unroll
    for (int i=0;i<NT;i++) Ereg[i] = __expf(Tl[i*NT + j]);
  }
  float a0 = (j<NT) ? emit[(long)(b*Ss)*NT + j] : -1e30f;
  float m = a0;
  #pragma unroll
  for (int off=1; off<64; off<<=1) m = fmaxf(m, __shfl_xor(m, off));
  float logZ = m;
  if (j<NT) A[j] = __expf(a0 - m);
  __syncthreads();

  for (int t=1;t<L;t++){
    float v = 0.f;
    if (j<NT){
      #pragma unroll
      for (int i=0;i<NT;i++) v = fmaf(A[i], Ereg[i], v);
      v *= __expf(emit[(long)(b*Ss+t)*NT + j]);
    }
    float mm = (j<NT) ? v : 0.f;
    #pragma unroll
    for (int off=1; off<64; off<<=1) mm = fmaxf(mm, __shfl_xor(mm, off));
    logZ += __logf(mm);
    float vn = v / mm;
    __syncthreads();
    if (j<NT) A[j] = vn;
    __syncthreads();
  }
  float s = (j<NT) ? A[j] : 0.f;
  #pragma unroll
  for (int off=1; off<64; off<<=1) s += __shfl_xor(s, off);
  float pred = logZ + __logf(s);
  if (tid==0) out[b] = pred - gold;
}

extern "C" void kernel_launch(void* const* d_in, const int* in_sizes, int n_in,
                              void* d_out, int out_size, void* d_ws, size_t ws_size,
                              hipStream_t stream){
  const int*   sentences = (const int*)d_in[0];
  const int*   lengths   = (const int*)d_in[1];
  const int*   words     = (const int*)d_in[2];
  const int*   tags      = (const int*)d_in[3];
  const float* char_emb  = (const float*)d_in[4];
  const float* cWi_f = (const float*)d_in[5];
  const float* cWh_f = (const float*)d_in[6];
  const float* cb_f  = (const float*)d_in[7];
  const float* cWi_b = (const float*)d_in[8];
  const float* cWh_b = (const float*)d_in[9];
  const float* cb_b  = (const float*)d_in[10];
  const float* word_emb = (const float*)d_in[11];
  const float* wWi_f = (const float*)d_in[12];
  const float* wWh_f = (const float*)d_in[13];
  const float* wb_f  = (const float*)d_in[14];
  const float* wWi_b = (const float*)d_in[15];
  const float* wWh_b = (const float*)d_in[16];
  const float* wb_b  = (const float*)d_in[17];
  const float* We   = (const float*)d_in[18];
  const float* be   = (const float*)d_in[19];
  const float* trans= (const float*)d_in[20];
  float* out = (float*)d_out;

  float* ws = (float*)d_ws;
  float* hf   = ws;                      // 8192*100
  float* hb   = hf  + 819200;
  float* x    = hb  + 819200;            // 8192*400
  float* gWf  = x   + 3276800;           // 8192*1024
  float* gWb  = gWf + 8388608;
  float* hfw  = gWb + 8388608;           // 8192*256
  float* hrw  = hfw + 2097152;
  float* emit = hrw + 2097152;           // 8192*50
  ushort_t* whPf = (ushort_t*)(emit + 409600);   // 1024*256 bf16
  ushort_t* whPb = whPf + 262144;

  k_cvt_wh<<<dim3(2048), 256, 0, stream>>>(wWh_f, wWh_b, whPf, whPb);
  k_char_mfma<<<dim3(256,2), 256, 0, stream>>>(words, char_emb,
      cWi_f, cWh_f, cb_f, hf,
      cWi_b, cWh_b, cb_b, hb);
  k_build_x<<<dim3(12800), 256, 0, stream>>>(sentences, word_emb, hf, hb, x);
  k_gemm<<<dim3(64,8,2), 256, 0, stream>>>(x, lengths, wWi_f, wb_f, gWf, wWi_b, wb_b, gWb);
  k_word<<<dim3(64,2), 256, 0, stream>>>(gWf, whPf, hfw, gWb, whPb, hrw);
  k_emit<<<dim3(64,8), 128, 0, stream>>>(hfw, hrw, lengths, We, be, emit);
  k_crf<<<dim3(64), 64, 0, stream>>>(emit, tags, lengths, trans, out);
}

// Round 3
// 937.212 us; speedup vs baseline: 3.1242x; 1.5057x over previous
//
#include <hip/hip_runtime.h>
#include <math.h>

#define Bb 64
#define Ss 128
#define BS 8192
#define Ww 16
#define CE 50
#define CH 100
#define EMBD 300
#define HID 256
#define WG 1024
#define XD 400
#define NT 50

typedef unsigned short ushort_t;
typedef unsigned int uint_t;
using bf16x8 = __attribute__((ext_vector_type(8))) short;
using short8v = __attribute__((ext_vector_type(8))) short;
using short4v = __attribute__((ext_vector_type(4))) short;
using f32x4  = __attribute__((ext_vector_type(4))) float;
using int4v  = __attribute__((ext_vector_type(4))) int;

__device__ __forceinline__ float sigf(float x){ return 1.0f/(1.0f+__expf(-x)); }
__device__ __forceinline__ float tanhfast(float x){
  float e = __expf(-2.0f*fabsf(x));
  float r = (1.0f-e)/(1.0f+e);
  return copysignf(r,x);
}
__device__ __forceinline__ float fsig(float x){
  float e = __builtin_amdgcn_exp2f(-1.4426950408889634f * x);
  return __builtin_amdgcn_rcpf(1.0f + e);
}
__device__ __forceinline__ float ftanh(float x){
  float e = __builtin_amdgcn_exp2f(-2.8853900817779268f * fabsf(x));
  float r = 1.0f - 2.0f*e*__builtin_amdgcn_rcpf(1.0f + e);
  return copysignf(r, x);
}
__device__ __forceinline__ ushort_t f2bf(float f){
  uint_t u = __float_as_uint(f);
  uint_t r = (u + 0x7fffu + ((u>>16)&1u)) >> 16;
  return (ushort_t)r;
}
__device__ __forceinline__ float bf2f(ushort_t u){ return __uint_as_float(((uint_t)u)<<16); }

// ---------------- Wh f32 -> row-scaled int8, gates-on-M layout: Whq[dir][m=j*4+g][k]
__global__ __launch_bounds__(256) void k_cvt_whq(const float* __restrict__ whf, const float* __restrict__ whb,
                                                 signed char* __restrict__ q, float* __restrict__ dm){
  const int tid = threadIdx.x;
  const int lane = tid & 63, w = tid >> 6;
  const int gm = blockIdx.x*4 + w;          // 0..2047
  const int dir = gm >> 10, m = gm & 1023;
  const float* src = dir ? whb : whf;
  const float* row = src + (long)((m&3)*HID + (m>>2)) * HID;
  float4 v = *(const float4*)&row[lane*4];
  float mx = fmaxf(fmaxf(fabsf(v.x), fabsf(v.y)), fmaxf(fabsf(v.z), fabsf(v.w)));
  #pragma unroll
  for (int off=32; off; off>>=1) mx = fmaxf(mx, __shfl_xor(mx, off));
  float s = (mx > 0.f) ? (127.0f / mx) : 0.f;
  int b0 = __float2int_rn(v.x*s) & 255;
  int b1 = __float2int_rn(v.y*s) & 255;
  int b2 = __float2int_rn(v.z*s) & 255;
  int b3 = __float2int_rn(v.w*s) & 255;
  uint_t pk = (uint_t)b0 | ((uint_t)b1<<8) | ((uint_t)b2<<16) | ((uint_t)b3<<24);
  *(uint_t*)&q[(long)gm*HID + lane*4] = pk;
  if (lane == 0) dm[gm] = mx * (1.0f/16129.0f);   // 127*127
}

// ---------------- char BiLSTM via MFMA (unchanged, verified round 2)
__global__ __launch_bounds__(256, 2) void k_char_mfma(const int* __restrict__ words, const float* __restrict__ cemb,
    const float* __restrict__ cWiF, const float* __restrict__ cWhF, const float* __restrict__ cbF, float* __restrict__ hfo,
    const float* __restrict__ cWiB, const float* __restrict__ cWhB, const float* __restrict__ cbB, float* __restrict__ hbo)
{
  const int rev = blockIdx.y;
  const float* cWi = rev ? cWiB : cWiF;
  const float* cWh = rev ? cWhB : cWhF;
  const float* cb  = rev ? cbB  : cbF;
  float* hout = rev ? hbo : hfo;
  const int n0 = blockIdx.x * 32;
  const int tid = threadIdx.x;
  const int lane = tid & 63;
  const int w = tid >> 6;

  __shared__ ushort_t xh[32][200];
  __shared__ ushort_t wi_l[400][72];
  __shared__ float    bias_l[400];
  __shared__ int      wbuf[32][Ww];

  for (int i = tid; i < 32*Ww; i += 256)
    wbuf[i>>4][i&15] = words[(n0 + (i>>4))*Ww + (i&15)];
  for (int i = tid; i < 3200; i += 256) ((uint_t*)xh)[i] = 0u;
  for (int r = tid; r < 400; r += 256){
    int j = r >> 2, g = r & 3;
    const float* src = cWi + (g*CH + j)*CE;
    for (int k = 0; k < 72; ++k)
      wi_l[r][k] = (k < CE) ? f2bf(src[k]) : (ushort_t)0;
    bias_l[r] = cb[g*CH + j];
  }

  bf16x8 whr[7][4];
  #pragma unroll
  for (int ti=0; ti<7; ++ti){
    int tm = w + ti*4;
    #pragma unroll
    for (int kk=0; kk<4; ++kk){
      bf16x8 v;
      #pragma unroll
      for (int e=0;e<8;++e) v[e]=0;
      if (tm < 25){
        int m = tm*16 + (lane & 15);
        int j = m >> 2, g = m & 3;
        const float* src = cWh + (g*CH + j)*CH;
        int kh0 = kk*32 + ((lane>>4)<<3);
        #pragma unroll
        for (int e=0;e<8;++e){
          int kh = kh0 + e;
          if (kh < CH) v[e] = (short)f2bf(src[kh]);
        }
      }
      whr[ti][kk] = v;
    }
  }

  float cst[7][2], hreg[7][2];
  #pragma unroll
  for (int ti=0; ti<7; ++ti){ cst[ti][0]=0.f; cst[ti][1]=0.f; hreg[ti][0]=0.f; hreg[ti][1]=0.f; }

  const int ps = tid >> 3;
  const int pk = (tid & 7) * 8;
  float xv[8];

  __syncthreads();

  {
    int tt = rev ? (Ww-1) : 0;
    int wd = wbuf[ps][tt];
    const float* src = cemb + wd*CE + pk;
    #pragma unroll
    for (int e=0;e<8;++e){ int k = pk+e; xv[e] = (k < CE) ? src[e] : 0.f; }
  }

  #pragma unroll 1
  for (int t=0; t<Ww; ++t){
    __syncthreads();
    if (t){
      #pragma unroll
      for (int ti=0; ti<7; ++ti){
        int tm = w + ti*4;
        if (tm < 25){
          int j = tm*4 + (lane>>4);
          #pragma unroll
          for (int nt=0; nt<2; ++nt){
            int s = nt*16 + (lane & 15);
            xh[s][64 + j] = f2bf(hreg[ti][nt]);
          }
        }
      }
    }
    {
      bf16x8 pxv;
      #pragma unroll
      for (int e=0;e<8;++e) pxv[e] = (short)f2bf(xv[e]);
      *((bf16x8*)&xh[ps][pk]) = pxv;
    }
    if (t+1 < Ww){
      int tt2 = rev ? (Ww-2-t) : (t+1);
      int wd = wbuf[ps][tt2];
      const float* src = cemb + wd*CE + pk;
      #pragma unroll
      for (int e=0;e<8;++e){ int k = pk+e; xv[e] = (k < CE) ? src[e] : 0.f; }
    }
    __syncthreads();

    bf16x8 bf[2][6];
    #pragma unroll
    for (int nt=0; nt<2; ++nt){
      int s = nt*16 + (lane & 15);
      #pragma unroll
      for (int kk=0; kk<6; ++kk){
        int k = kk*32 + ((lane>>4)<<3);
        bf[nt][kk] = *((const bf16x8*)&xh[s][k]);
      }
    }
    #pragma unroll
    for (int ti=0; ti<7; ++ti){
      int tm = w + ti*4;
      if (tm < 25){
        int row = tm*16 + (lane & 15);
        int kb = (lane>>4)<<3;
        bf16x8 awi0 = *((const bf16x8*)&wi_l[row][kb]);
        bf16x8 awi1 = *((const bf16x8*)&wi_l[row][32+kb]);
        f32x4 bias_v = *((const f32x4*)&bias_l[tm*16 + ((lane>>4)<<2)]);
        #pragma unroll
        for (int nt=0; nt<2; ++nt){
          f32x4 acc = bias_v;
          acc = __builtin_amdgcn_mfma_f32_16x16x32_bf16(awi0, bf[nt][0], acc, 0,0,0);
          acc = __builtin_amdgcn_mfma_f32_16x16x32_bf16(awi1, bf[nt][1], acc, 0,0,0);
          #pragma unroll
          for (int kk=0; kk<4; ++kk)
            acc = __builtin_amdgcn_mfma_f32_16x16x32_bf16(whr[ti][kk], bf[nt][2+kk], acc, 0,0,0);
          float iv = sigf(acc[0]), fv = sigf(acc[1]);
          float gv = tanhfast(acc[2]), ov = sigf(acc[3]);
          float cn = fmaf(fv, cst[ti][nt], iv*gv);
          cst[ti][nt] = cn;
          hreg[ti][nt] = ov * tanhfast(cn);
        }
      }
    }
  }

  #pragma unroll
  for (int ti=0; ti<7; ++ti){
    int tm = w + ti*4;
    if (tm < 25){
      int j = tm*4 + (lane>>4);
      #pragma unroll
      for (int nt=0; nt<2; ++nt){
        int s = nt*16 + (lane & 15);
        hout[(n0 + s)*CH + j] = hreg[ti][nt];
      }
    }
  }
}

// ---------------- x = [word_emb gather | hf+hb]
__global__ void k_build_x(const int* __restrict__ sent, const float* __restrict__ wemb,
                          const float* __restrict__ hf, const float* __restrict__ hb,
                          float* __restrict__ x){
  long i = (long)blockIdx.x*256 + threadIdx.x;
  if (i >= (long)BS*XD) return;
  int n = (int)(i / XD), e = (int)(i - (long)n*XD);
  float v;
  if (e < EMBD) v = wemb[(long)sent[n]*EMBD + e];
  else { int jj = e-EMBD; v = hf[n*CH+jj] + hb[n*CH+jj]; }
  x[i] = v;
}

// ---------------- word input-gate GEMM -> bf16 gW ; rev folds xr remap
__global__ __launch_bounds__(256) void k_gemm(const float* __restrict__ x, const int* __restrict__ lengths,
    const float* __restrict__ WiF, const float* __restrict__ wbF, ushort_t* __restrict__ goutF,
    const float* __restrict__ WiB, const float* __restrict__ wbB, ushort_t* __restrict__ goutB)
{
  const int rev = blockIdx.z;
  const float* Wi  = rev ? WiB  : WiF;
  const float* bias= rev ? wbB  : wbF;
  ushort_t* gout   = rev ? goutB: goutF;

  const int m0 = blockIdx.x * 128, n0 = blockIdx.y * 128;
  const int b  = m0 >> 7;
  const int L  = lengths[b];

  __shared__ float Al[16][132];
  __shared__ float Bl[16][132];
  const int tid = threadIdx.x;
  const int tx = tid & 15, ty = tid >> 4;
  const int r0 = ty*8, c0 = tx*8;

  float acc[8][8];
  #pragma unroll
  for (int i=0;i<8;i++)
    #pragma unroll
    for (int q=0;q<8;q++) acc[i][q]=0.f;

  float bv[8];
  #pragma unroll
  for (int q=0;q<8;q++) bv[q] = bias[n0+c0+q];

  for (int k0=0;k0<XD;k0+=16){
    #pragma unroll
    for (int u=0;u<2;u++){
      int idx = tid*2+u;
      int r = idx>>2, kq = idx&3;
      bool zz = false; int srcrow;
      if (!rev) srcrow = m0 + r;
      else { if (r < L) srcrow = b*Ss + (L-1-r); else { zz = true; srcrow = b*Ss; } }
      float4 v = make_float4(0.f,0.f,0.f,0.f);
      if (!zz) v = *(const float4*)&x[(long)srcrow*XD + k0 + kq*4];
      Al[kq*4+0][r]=v.x; Al[kq*4+1][r]=v.y; Al[kq*4+2][r]=v.z; Al[kq*4+3][r]=v.w;
    }
    {
      int kk = tid & 15, ng = tid >> 4;
      #pragma unroll
      for (int u=0;u<8;u++){
        int nn = ng*8+u;
        Bl[kk][nn] = Wi[(long)(n0+nn)*XD + k0 + kk];
      }
    }
    __syncthreads();
    #pragma unroll
    for (int kk=0;kk<16;kk++){
      float4 a0 = *(const float4*)&Al[kk][r0];
      float4 a1 = *(const float4*)&Al[kk][r0+4];
      float4 b0 = *(const float4*)&Bl[kk][c0];
      float4 b1 = *(const float4*)&Bl[kk][c0+4];
      float av[8] = {a0.x,a0.y,a0.z,a0.w,a1.x,a1.y,a1.z,a1.w};
      float bw[8] = {b0.x,b0.y,b0.z,b0.w,b1.x,b1.y,b1.z,b1.w};
      #pragma unroll
      for (int i=0;i<8;i++)
        #pragma unroll
        for (int q=0;q<8;q++) acc[i][q] = fmaf(av[i], bw[q], acc[i][q]);
    }
    __syncthreads();
  }
  #pragma unroll
  for (int i=0;i<8;i++){
    int row = m0 + r0 + i;
    short8v o;
    #pragma unroll
    for (int q=0;q<8;q++) o[q] = (short)f2bf(acc[i][q]+bv[q]);
    *(short8v*)&gout[(long)row*WG + n0 + c0] = o;
  }
}

// ---------------- pack gW (bf16, [seq*128+t][g*256+j]) -> P[dir][t][sb][sl][m=j*4+g]
__global__ void k_gw_pack(const ushort_t* __restrict__ gwF, const ushort_t* __restrict__ gwB,
                          ushort_t* __restrict__ P){
  uint_t idx = blockIdx.x*256 + threadIdx.x;   // < 16,777,216
  uint_t m = idx & 1023;
  uint_t r = idx >> 10;
  uint_t sl = r & 3; r >>= 2;
  uint_t sb = r & 15; r >>= 4;
  uint_t t = r & 127;
  uint_t dir = r >> 7;
  const ushort_t* src = dir ? gwB : gwF;
  P[idx] = src[(long)((sb*4+sl)*128 + t)*WG + ((m&3)*HID) + (m>>2)];
}

// ---------------- word LSTM recurrence via int8 MFMA; Wh resident in registers.
// Grid: (16 sb, 2 dir), 512 threads (8 waves). Wave w owns M-tiles tm=w*8+ti (ti 0..7).
// Lane: hi=lane>>4 (0..3), lo=lane&15 (seq slot; slots 4..15 duplicate 0..3).
__global__ __launch_bounds__(512, 2) void k_word_i8(
    const signed char* __restrict__ whq, const float* __restrict__ dmg,
    const ushort_t* __restrict__ P, float* __restrict__ hfw, float* __restrict__ hrw)
{
  const int dir = blockIdx.y, sb = blockIdx.x;
  const int tid = threadIdx.x, lane = tid & 63, w = tid >> 6;
  float* hout = dir ? hrw : hfw;

  __shared__ signed char hq[2][16][272];
  for (int i = tid; i < 2176; i += 512) ((int*)hq)[i] = 0;

  const int hi = lane >> 4;
  const int lo = lane & 15;
  const int slc = lo & 3;

  long wfr[8][8];
  f32x4 dmq[8];
  #pragma unroll
  for (int ti=0; ti<8; ++ti){
    int tm = w*8 + ti;
    int mA = tm*16 + lo;
    #pragma unroll
    for (int kf=0; kf<8; ++kf)
      wfr[ti][kf] = *(const long*)&whq[(long)(dir*1024 + mA)*HID + kf*32 + hi*8];
    int mD = tm*16 + hi*4;
    dmq[ti] = *(const f32x4*)&dmg[dir*1024 + mD];
  }
  float cst[8];
  #pragma unroll
  for (int ti=0; ti<8; ++ti) cst[ti] = 0.f;

  const ushort_t* Pd = P + (long)dir*8388608 + (long)(sb*4 + slc)*1024;
  short4v g_cur[8], g_nxt[8];
  #pragma unroll
  for (int ti=0; ti<8; ++ti)
    g_cur[ti] = *(const short4v*)&Pd[(w*8+ti)*16 + hi*4];

  int p = 0;
  const int nbase = sb*4 + lo;

  #pragma unroll 1
  for (int t=0; t<Ss; ++t){
    __syncthreads();
    long bfr[8];
    #pragma unroll
    for (int kf=0; kf<8; ++kf)
      bfr[kf] = *(const long*)&hq[p][lo][kf*32 + hi*8];
    if (t < Ss-1){
      #pragma unroll
      for (int ti=0; ti<8; ++ti)
        g_nxt[ti] = *(const short4v*)&Pd[(long)(t+1)*65536 + (w*8+ti)*16 + hi*4];
    }
    #pragma unroll
    for (int ti=0; ti<8; ++ti){
      int4v acc = {0,0,0,0};
      #pragma unroll
      for (int kf=0; kf<8; ++kf)
        acc = __builtin_amdgcn_mfma_i32_16x16x32_i8(wfr[ti][kf], bfr[kf], acc, 0,0,0);
      float g0 = (float)acc[0]*dmq[ti][0] + bf2f((ushort_t)g_cur[ti][0]);
      float g1 = (float)acc[1]*dmq[ti][1] + bf2f((ushort_t)g_cur[ti][1]);
      float g2 = (float)acc[2]*dmq[ti][2] + bf2f((ushort_t)g_cur[ti][2]);
      float g3 = (float)acc[3]*dmq[ti][3] + bf2f((ushort_t)g_cur[ti][3]);
      float iv = fsig(g0), fv = fsig(g1), gv = ftanh(g2), ov = fsig(g3);
      float cn = fmaf(fv, cst[ti], iv*gv);
      cst[ti] = cn;
      float hn = ov * ftanh(cn);
      int j = (w*8+ti)*4 + hi;
      if (lo < 4) hout[((long)nbase*Ss + t)*HID + j] = hn;
      hq[1-p][lo][j] = (signed char)__float2int_rn(hn * 127.0f);
    }
    #pragma unroll
    for (int ti=0; ti<8; ++ti) g_cur[ti] = g_nxt[ti];
    p ^= 1;
  }
}

// ---------------- emissions: emit = concat(h_fwd, h_bwd)*valid @ We^T + be
__global__ __launch_bounds__(128) void k_emit(const float* __restrict__ hfw, const float* __restrict__ hrw,
    const int* __restrict__ lengths, const float* __restrict__ We, const float* __restrict__ be,
    float* __restrict__ emit)
{
  __shared__ float Wl[NT*516];
  const int b = blockIdx.x, tg = blockIdx.y;
  const int tid = threadIdx.x;
  for (int i = tid; i < NT*512; i += 128)
    Wl[(i>>9)*516 + (i&511)] = We[i];
  __syncthreads();
  const int L = lengths[b];
  const int j = tid & 63;
  const int th = tid >> 6;
  float bej = (j<NT) ? be[j] : 0.f;
  for (int ttq=0; ttq<8; ttq++){
    int t = tg*16 + th*8 + ttq;
    int n = b*Ss + t;
    float acc = bej;
    if (j < NT && t < L){
      const float* hf_ = hfw + (long)n*HID;
      const float* hb_ = hrw + (long)(b*Ss + (L-1-t))*HID;
      const float* wr = Wl + j*516;
      for (int k=0;k<HID;k+=4){
        float4 hv = *(const float4*)(hf_+k);
        float4 wv = *(const float4*)(wr+k);
        acc += hv.x*wv.x + hv.y*wv.y + hv.z*wv.z + hv.w*wv.w;
      }
      for (int k=0;k<HID;k+=4){
        float4 hv = *(const float4*)(hb_+k);
        float4 wv = *(const float4*)(wr+256+k);
        acc += hv.x*wv.x + hv.y*wv.y + hv.z*wv.z + hv.w*wv.w;
      }
    }
    if (j < NT) emit[(long)n*NT + j] = acc;
  }
}

// ---------------- CRF: gold score + exp-domain forward algorithm; out = pred - gold
__global__ __launch_bounds__(64) void k_crf(const float* __restrict__ emit, const int* __restrict__ tags,
    const int* __restrict__ lengths, const float* __restrict__ trans, float* __restrict__ out)
{
  const int b = blockIdx.x;
  const int tid = threadIdx.x;
  __shared__ float Tl[NT*NT];
  __shared__ float A[NT];
  __shared__ float red[64];
  for (int i=tid;i<NT*NT;i+=64) Tl[i] = trans[i];
  __syncthreads();
  const int L = lengths[b];

  float gp = 0.f;
  for (int t=tid; t<L; t+=64){
    int tg = tags[b*Ss+t];
    gp += emit[(long)(b*Ss+t)*NT + tg];
    if (t>=1) gp += Tl[tags[b*Ss+t-1]*NT + tg];
  }
  red[tid] = gp; __syncthreads();
  for (int off=32; off; off>>=1){ if (tid<off) red[tid]+=red[tid+off]; __syncthreads(); }
  float gold = red[0];

  const int j = tid;
  float Ereg[NT];
  if (j < NT){
    #pragma unroll
    for (int i=0;i<NT;i++) Ereg[i] = __expf(Tl[i*NT + j]);
  }
  float a0 = (j<NT) ? emit[(long)(b*Ss)*NT + j] : -1e30f;
  float m = a0;
  #pragma unroll
  for (int off=1; off<64; off<<=1) m = fmaxf(m, __shfl_xor(m, off));
  float logZ = m;
  if (j<NT) A[j] = __expf(a0 - m);
  __syncthreads();

  for (int t=1;t<L;t++){
    float v = 0.f;
    if (j<NT){
      #pragma unroll
      for (int i=0;i<NT;i++) v = fmaf(A[i], Ereg[i], v);
      v *= __expf(emit[(long)(b*Ss+t)*NT + j]);
    }
    float mm = (j<NT) ? v : 0.f;
    #pragma unroll
    for (int off=1; off<64; off<<=1) mm = fmaxf(mm, __shfl_xor(mm, off));
    logZ += __logf(mm);
    float vn = v / mm;
    __syncthreads();
    if (j<NT) A[j] = vn;
    __syncthreads();
  }
  float s = (j<NT) ? A[j] : 0.f;
  #pragma unroll
  for (int off=1; off<64; off<<=1) s += __shfl_xor(s, off);
  float pred = logZ + __logf(s);
  if (tid==0) out[b] = pred - gold;
}

extern "C" void kernel_launch(void* const* d_in, const int* in_sizes, int n_in,
                              void* d_out, int out_size, void* d_ws, size_t ws_size,
                              hipStream_t stream){
  const int*   sentences = (const int*)d_in[0];
  const int*   lengths   = (const int*)d_in[1];
  const int*   words     = (const int*)d_in[2];
  const int*   tags      = (const int*)d_in[3];
  const float* char_emb  = (const float*)d_in[4];
  const float* cWi_f = (const float*)d_in[5];
  const float* cWh_f = (const float*)d_in[6];
  const float* cb_f  = (const float*)d_in[7];
  const float* cWi_b = (const float*)d_in[8];
  const float* cWh_b = (const float*)d_in[9];
  const float* cb_b  = (const float*)d_in[10];
  const float* word_emb = (const float*)d_in[11];
  const float* wWi_f = (const float*)d_in[12];
  const float* wWh_f = (const float*)d_in[13];
  const float* wb_f  = (const float*)d_in[14];
  const float* wWi_b = (const float*)d_in[15];
  const float* wWh_b = (const float*)d_in[16];
  const float* wb_b  = (const float*)d_in[17];
  const float* We   = (const float*)d_in[18];
  const float* be   = (const float*)d_in[19];
  const float* trans= (const float*)d_in[20];
  float* out = (float*)d_out;

  float* ws = (float*)d_ws;
  float* hf   = ws;                               // 819200 f32
  float* hb   = hf  + 819200;                     // 819200 f32
  float* x    = hb  + 819200;                     // 3276800 f32
  ushort_t* gwF = (ushort_t*)(x + 3276800);       // 8388608 bf16
  ushort_t* gwB = gwF + 8388608;                  // 8388608 bf16
  ushort_t* P   = gwB + 8388608;                  // 16777216 bf16
  float* hfw  = (float*)(P + 16777216);           // 2097152 f32
  float* hrw  = hfw + 2097152;                    // 2097152 f32
  float* emit = hrw + 2097152;                    // 409600 f32
  signed char* whq = (signed char*)(emit + 409600); // 524288 i8
  float* dm   = (float*)(whq + 524288);           // 2048 f32

  k_cvt_whq<<<dim3(512), 256, 0, stream>>>(wWh_f, wWh_b, whq, dm);
  k_char_mfma<<<dim3(256,2), 256, 0, stream>>>(words, char_emb,
      cWi_f, cWh_f, cb_f, hf,
      cWi_b, cWh_b, cb_b, hb);
  k_build_x<<<dim3(12800), 256, 0, stream>>>(sentences, word_emb, hf, hb, x);
  k_gemm<<<dim3(64,8,2), 256, 0, stream>>>(x, lengths, wWi_f, wb_f, gwF, wWi_b, wb_b, gwB);
  k_gw_pack<<<dim3(65536), 256, 0, stream>>>(gwF, gwB, P);
  k_word_i8<<<dim3(16,2), 512, 0, stream>>>(whq, dm, P, hfw, hrw);
  k_emit<<<dim3(64,8), 128, 0, stream>>>(hfw, hrw, lengths, We, be, emit);
  k_crf<<<dim3(64), 64, 0, stream>>>(emit, tags, lengths, trans, out);
}

// Round 4
// 546.106 us; speedup vs baseline: 5.3616x; 1.7162x over previous
//
#include <hip/hip_runtime.h>
#include <math.h>

#define Bb 64
#define Ss 128
#define BS 8192
#define Ww 16
#define CE 50
#define CH 100
#define EMBD 300
#define HID 256
#define WG 1024
#define XD 400
#define XDP 416
#define NT 50

typedef unsigned short ushort_t;
typedef unsigned int uint_t;
using bf16x8 = __attribute__((ext_vector_type(8))) short;
using short8v = __attribute__((ext_vector_type(8))) short;
using short4v = __attribute__((ext_vector_type(4))) short;
using f32x4  = __attribute__((ext_vector_type(4))) float;
using int4v  = __attribute__((ext_vector_type(4))) int;

#define LBAR() do { asm volatile("s_waitcnt lgkmcnt(0)" ::: "memory"); __builtin_amdgcn_s_barrier(); } while(0)

__device__ __forceinline__ float sigf(float x){ return 1.0f/(1.0f+__expf(-x)); }
__device__ __forceinline__ float tanhfast(float x){
  float e = __expf(-2.0f*fabsf(x));
  float r = (1.0f-e)/(1.0f+e);
  return copysignf(r,x);
}
__device__ __forceinline__ float fsig(float x){
  float e = __builtin_amdgcn_exp2f(-1.4426950408889634f * x);
  return __builtin_amdgcn_rcpf(1.0f + e);
}
__device__ __forceinline__ float ftanh(float x){
  float e = __builtin_amdgcn_exp2f(-2.8853900817779268f * fabsf(x));
  float r = 1.0f - 2.0f*e*__builtin_amdgcn_rcpf(1.0f + e);
  return copysignf(r, x);
}
__device__ __forceinline__ ushort_t f2bf(float f){
  uint_t u = __float_as_uint(f);
  uint_t r = (u + 0x7fffu + ((u>>16)&1u)) >> 16;
  return (ushort_t)r;
}
__device__ __forceinline__ float bf2f(ushort_t u){ return __uint_as_float(((uint_t)u)<<16); }

__device__ __forceinline__ int4v sel4(int c, int4v a, int4v b){
  int4v r;
  #pragma unroll
  for (int i=0;i<4;i++) r[i] = c ? a[i] : b[i];
  return r;
}

// ---------------- Wh f32 -> row-scaled int8, gates-on-M layout: Whq[dir][m=j*4+g][k]
__global__ __launch_bounds__(256) void k_cvt_whq(const float* __restrict__ whf, const float* __restrict__ whb,
                                                 signed char* __restrict__ q, float* __restrict__ dm){
  const int tid = threadIdx.x;
  const int lane = tid & 63, w = tid >> 6;
  const int gm = blockIdx.x*4 + w;          // 0..2047
  const int dir = gm >> 10, m = gm & 1023;
  const float* src = dir ? whb : whf;
  const float* row = src + (long)((m&3)*HID + (m>>2)) * HID;
  float4 v = *(const float4*)&row[lane*4];
  float mx = fmaxf(fmaxf(fabsf(v.x), fabsf(v.y)), fmaxf(fabsf(v.z), fabsf(v.w)));
  #pragma unroll
  for (int off=32; off; off>>=1) mx = fmaxf(mx, __shfl_xor(mx, off));
  float s = (mx > 0.f) ? (127.0f / mx) : 0.f;
  int b0 = __float2int_rn(v.x*s) & 255;
  int b1 = __float2int_rn(v.y*s) & 255;
  int b2 = __float2int_rn(v.z*s) & 255;
  int b3 = __float2int_rn(v.w*s) & 255;
  uint_t pk = (uint_t)b0 | ((uint_t)b1<<8) | ((uint_t)b2<<16) | ((uint_t)b3<<24);
  *(uint_t*)&q[(long)gm*HID + lane*4] = pk;
  if (lane == 0) dm[gm] = mx * (1.0f/16129.0f);   // 127*127
}

// ---------------- char BiLSTM via MFMA (unchanged, verified round 2)
__global__ __launch_bounds__(256, 2) void k_char_mfma(const int* __restrict__ words, const float* __restrict__ cemb,
    const float* __restrict__ cWiF, const float* __restrict__ cWhF, const float* __restrict__ cbF, float* __restrict__ hfo,
    const float* __restrict__ cWiB, const float* __restrict__ cWhB, const float* __restrict__ cbB, float* __restrict__ hbo)
{
  const int rev = blockIdx.y;
  const float* cWi = rev ? cWiB : cWiF;
  const float* cWh = rev ? cWhB : cWhF;
  const float* cb  = rev ? cbB  : cbF;
  float* hout = rev ? hbo : hfo;
  const int n0 = blockIdx.x * 32;
  const int tid = threadIdx.x;
  const int lane = tid & 63;
  const int w = tid >> 6;

  __shared__ ushort_t xh[32][200];
  __shared__ ushort_t wi_l[400][72];
  __shared__ float    bias_l[400];
  __shared__ int      wbuf[32][Ww];

  for (int i = tid; i < 32*Ww; i += 256)
    wbuf[i>>4][i&15] = words[(n0 + (i>>4))*Ww + (i&15)];
  for (int i = tid; i < 3200; i += 256) ((uint_t*)xh)[i] = 0u;
  for (int r = tid; r < 400; r += 256){
    int j = r >> 2, g = r & 3;
    const float* src = cWi + (g*CH + j)*CE;
    for (int k = 0; k < 72; ++k)
      wi_l[r][k] = (k < CE) ? f2bf(src[k]) : (ushort_t)0;
    bias_l[r] = cb[g*CH + j];
  }

  bf16x8 whr[7][4];
  #pragma unroll
  for (int ti=0; ti<7; ++ti){
    int tm = w + ti*4;
    #pragma unroll
    for (int kk=0; kk<4; ++kk){
      bf16x8 v;
      #pragma unroll
      for (int e=0;e<8;++e) v[e]=0;
      if (tm < 25){
        int m = tm*16 + (lane & 15);
        int j = m >> 2, g = m & 3;
        const float* src = cWh + (g*CH + j)*CH;
        int kh0 = kk*32 + ((lane>>4)<<3);
        #pragma unroll
        for (int e=0;e<8;++e){
          int kh = kh0 + e;
          if (kh < CH) v[e] = (short)f2bf(src[kh]);
        }
      }
      whr[ti][kk] = v;
    }
  }

  float cst[7][2], hreg[7][2];
  #pragma unroll
  for (int ti=0; ti<7; ++ti){ cst[ti][0]=0.f; cst[ti][1]=0.f; hreg[ti][0]=0.f; hreg[ti][1]=0.f; }

  const int ps = tid >> 3;
  const int pk = (tid & 7) * 8;
  float xv[8];

  __syncthreads();

  {
    int tt = rev ? (Ww-1) : 0;
    int wd = wbuf[ps][tt];
    const float* src = cemb + wd*CE + pk;
    #pragma unroll
    for (int e=0;e<8;++e){ int k = pk+e; xv[e] = (k < CE) ? src[e] : 0.f; }
  }

  #pragma unroll 1
  for (int t=0; t<Ww; ++t){
    __syncthreads();
    if (t){
      #pragma unroll
      for (int ti=0; ti<7; ++ti){
        int tm = w + ti*4;
        if (tm < 25){
          int j = tm*4 + (lane>>4);
          #pragma unroll
          for (int nt=0; nt<2; ++nt){
            int s = nt*16 + (lane & 15);
            xh[s][64 + j] = f2bf(hreg[ti][nt]);
          }
        }
      }
    }
    {
      bf16x8 pxv;
      #pragma unroll
      for (int e=0;e<8;++e) pxv[e] = (short)f2bf(xv[e]);
      *((bf16x8*)&xh[ps][pk]) = pxv;
    }
    if (t+1 < Ww){
      int tt2 = rev ? (Ww-2-t) : (t+1);
      int wd = wbuf[ps][tt2];
      const float* src = cemb + wd*CE + pk;
      #pragma unroll
      for (int e=0;e<8;++e){ int k = pk+e; xv[e] = (k < CE) ? src[e] : 0.f; }
    }
    __syncthreads();

    bf16x8 bf[2][6];
    #pragma unroll
    for (int nt=0; nt<2; ++nt){
      int s = nt*16 + (lane & 15);
      #pragma unroll
      for (int kk=0; kk<6; ++kk){
        int k = kk*32 + ((lane>>4)<<3);
        bf[nt][kk] = *((const bf16x8*)&xh[s][k]);
      }
    }
    #pragma unroll
    for (int ti=0; ti<7; ++ti){
      int tm = w + ti*4;
      if (tm < 25){
        int row = tm*16 + (lane & 15);
        int kb = (lane>>4)<<3;
        bf16x8 awi0 = *((const bf16x8*)&wi_l[row][kb]);
        bf16x8 awi1 = *((const bf16x8*)&wi_l[row][32+kb]);
        f32x4 bias_v = *((const f32x4*)&bias_l[tm*16 + ((lane>>4)<<2)]);
        #pragma unroll
        for (int nt=0; nt<2; ++nt){
          f32x4 acc = bias_v;
          acc = __builtin_amdgcn_mfma_f32_16x16x32_bf16(awi0, bf[nt][0], acc, 0,0,0);
          acc = __builtin_amdgcn_mfma_f32_16x16x32_bf16(awi1, bf[nt][1], acc, 0,0,0);
          #pragma unroll
          for (int kk=0; kk<4; ++kk)
            acc = __builtin_amdgcn_mfma_f32_16x16x32_bf16(whr[ti][kk], bf[nt][2+kk], acc, 0,0,0);
          float iv = sigf(acc[0]), fv = sigf(acc[1]);
          float gv = tanhfast(acc[2]), ov = sigf(acc[3]);
          float cn = fmaf(fv, cst[ti][nt], iv*gv);
          cst[ti][nt] = cn;
          hreg[ti][nt] = ov * tanhfast(cn);
        }
      }
    }
  }

  #pragma unroll
  for (int ti=0; ti<7; ++ti){
    int tm = w + ti*4;
    if (tm < 25){
      int j = tm*4 + (lane>>4);
      #pragma unroll
      for (int nt=0; nt<2; ++nt){
        int s = nt*16 + (lane & 15);
        hout[(n0 + s)*CH + j] = hreg[ti][nt];
      }
    }
  }
}

// ---------------- xbf = [word_emb gather | hf+hb | 0-pad], bf16 [8192][416]
__global__ void k_build_x(const int* __restrict__ sent, const float* __restrict__ wemb,
                          const float* __restrict__ hf, const float* __restrict__ hb,
                          ushort_t* __restrict__ xbf){
  long i = (long)blockIdx.x*256 + threadIdx.x;
  if (i >= (long)BS*XDP) return;
  int n = (int)(i / XDP), e = (int)(i - (long)n*XDP);
  float v = 0.f;
  if (e < EMBD) v = wemb[(long)sent[n]*EMBD + e];
  else if (e < XD) { int jj = e-EMBD; v = hf[n*CH+jj] + hb[n*CH+jj]; }
  xbf[i] = f2bf(v);
}

// ---------------- Wi f32 -> bf16 padded: wiP[dir][1024][416]
__global__ void k_cvt_wi(const float* __restrict__ wiF, const float* __restrict__ wiB,
                         ushort_t* __restrict__ wiP){
  int i = blockIdx.x*256 + threadIdx.x;
  if (i >= 2*WG*XDP) return;
  int dir = i >= WG*XDP;
  int ii = dir ? i - WG*XDP : i;
  int n = ii / XDP, k = ii - n*XDP;
  const float* src = dir ? wiB : wiF;
  wiP[i] = (k < XD) ? f2bf(src[n*XD + k]) : (ushort_t)0;
}

// ---------------- word input-gate GEMM via bf16 MFMA: gout[8192,1024] bf16; rev folds xr remap
__global__ __launch_bounds__(256) void k_gemm_mfma(const ushort_t* __restrict__ xbf, const int* __restrict__ lengths,
    const ushort_t* __restrict__ wiP, const float* __restrict__ wbF, const float* __restrict__ wbB,
    ushort_t* __restrict__ goutF, ushort_t* __restrict__ goutB)
{
  const int rev = blockIdx.z;
  const int b = blockIdx.x;
  const int n0 = blockIdx.y * 128;
  const float* bias = rev ? wbB : wbF;
  ushort_t* gout = rev ? goutB : goutF;
  const int m0 = b*Ss;
  const int L = lengths[b];

  __shared__ ushort_t As[128*32];
  __shared__ ushort_t Bs[128*32];
  __shared__ float bl[128];

  const int tid = threadIdx.x;
  const int lane = tid & 63, w = tid >> 6;
  const int lo = lane & 15, hi = lane >> 4;
  const int wm0 = (w>>1)*64, wn0 = (w&1)*64;

  if (tid < 128) bl[tid] = bias[n0 + tid];

  long abase[2], bbase[2];
  #pragma unroll
  for (int u=0; u<2; ++u){
    int cid = u*256 + tid;
    int r = cid >> 2, kc = (cid & 3)*8;
    int srow;
    if (!rev) srow = m0 + r;
    else { int rr = L-1-r; srow = m0 + (rr < 0 ? 0 : rr); }
    abase[u] = (long)srow*XDP + kc;
    bbase[u] = ((long)rev*WG + n0 + r)*XDP + kc;
  }

  f32x4 acc[4][4];
  #pragma unroll
  for (int i=0;i<4;i++)
    #pragma unroll
    for (int q=0;q<4;q++){ acc[i][q][0]=0.f; acc[i][q][1]=0.f; acc[i][q][2]=0.f; acc[i][q][3]=0.f; }

  bf16x8 avn[2], bvn[2];
  #pragma unroll
  for (int u=0; u<2; ++u){
    avn[u] = *(const bf16x8*)&xbf[abase[u]];
    bvn[u] = *(const bf16x8*)&wiP[bbase[u]];
  }

  #pragma unroll 1
  for (int kt=0; kt<13; ++kt){
    bf16x8 av[2], bv[2];
    #pragma unroll
    for (int u=0; u<2; ++u){ av[u]=avn[u]; bv[u]=bvn[u]; }
    if (kt < 12){
      int k0 = (kt+1)*32;
      #pragma unroll
      for (int u=0; u<2; ++u){
        avn[u] = *(const bf16x8*)&xbf[abase[u] + k0];
        bvn[u] = *(const bf16x8*)&wiP[bbase[u] + k0];
      }
    }
    LBAR();   // all frag reads of previous tile done
    #pragma unroll
    for (int u=0; u<2; ++u){
      *(bf16x8*)&As[(u*256 + tid)*8] = av[u];
      *(bf16x8*)&Bs[(u*256 + tid)*8] = bv[u];
    }
    LBAR();   // writes visible
    bf16x8 af[4], bfr[4];
    #pragma unroll
    for (int mt=0; mt<4; ++mt) af[mt] = *(const bf16x8*)&As[(wm0 + mt*16 + lo)*32 + hi*8];
    #pragma unroll
    for (int nt=0; nt<4; ++nt) bfr[nt] = *(const bf16x8*)&Bs[(wn0 + nt*16 + lo)*32 + hi*8];
    #pragma unroll
    for (int mt=0; mt<4; ++mt)
      #pragma unroll
      for (int nt=0; nt<4; ++nt)
        acc[mt][nt] = __builtin_amdgcn_mfma_f32_16x16x32_bf16(af[mt], bfr[nt], acc[mt][nt], 0,0,0);
  }

  LBAR();
  #pragma unroll
  for (int nt=0; nt<4; ++nt){
    float bn = bl[wn0 + nt*16 + lo];
    #pragma unroll
    for (int mt=0; mt<4; ++mt){
      #pragma unroll
      for (int r=0; r<4; ++r){
        int m = m0 + wm0 + mt*16 + hi*4 + r;
        int n = n0 + wn0 + nt*16 + lo;
        gout[(long)m*WG + n] = f2bf(acc[mt][nt][r] + bn);
      }
    }
  }
}

// ---------------- pack gW (bf16, [seq*128+t][g*256+j]) -> P[dir][t][sb][sl][m=j*4+g]
__global__ void k_gw_pack(const ushort_t* __restrict__ gwF, const ushort_t* __restrict__ gwB,
                          ushort_t* __restrict__ P){
  uint_t idx = blockIdx.x*256 + threadIdx.x;   // < 16,777,216
  uint_t m = idx & 1023;
  uint_t r = idx >> 10;
  uint_t sl = r & 3; r >>= 2;
  uint_t sb = r & 15; r >>= 4;
  uint_t t = r & 127;
  uint_t dir = r >> 7;
  const ushort_t* src = dir ? gwB : gwF;
  P[idx] = src[(long)((sb*4+sl)*128 + t)*WG + ((m&3)*HID) + (m>>2)];
}

// ---------------- word LSTM recurrence via int8 MFMA; Wh resident in registers.
// Grid: (16 sb, 2 dir), 512 threads (8 waves). Wave w owns M-tiles w*8..w*8+7.
// Lane (hi=lane>>4, lo=lane&15): sq=lo&3 (seq), g2=lo>>2 selects the lane's 2 owned tiles.
__global__ __launch_bounds__(512, 2) void k_word_i8(
    const signed char* __restrict__ whq, const float* __restrict__ dmg,
    const ushort_t* __restrict__ P, float* __restrict__ hfw, float* __restrict__ hrw)
{
  const int dir = blockIdx.y, sb = blockIdx.x;
  const int tid = threadIdx.x, lane = tid & 63, w = tid >> 6;
  float* hout = dir ? hrw : hfw;

  __shared__ signed char hq[2][4][272];
  if (tid < 272) ((int*)hq)[tid] = 0;     // zero hq[0] (1088 B)

  const int hi = lane >> 4;
  const int lo = lane & 15;
  const int sq = lo & 3;
  const int g2 = lo >> 2;

  long wfr[8][8];
  #pragma unroll
  for (int ti=0; ti<8; ++ti){
    int mA = (w*8+ti)*16 + lo;
    #pragma unroll
    for (int kf=0; kf<8; ++kf)
      wfr[ti][kf] = *(const long*)&whq[(dir*1024 + mA)*HID + kf*32 + hi*8];
  }
  f32x4 dmq[2];
  #pragma unroll
  for (int u=0; u<2; ++u)
    dmq[u] = *(const f32x4*)&dmg[dir*1024 + (w*8 + g2*2+u)*16 + hi*4];

  float cst[2] = {0.f, 0.f};

  const ushort_t* Pd = P + (long)dir*8388608 + (sb*4 + sq)*1024;
  const ushort_t* gp0 = Pd + (w*8 + g2*2+0)*16 + hi*4;
  const ushort_t* gp1 = Pd + (w*8 + g2*2+1)*16 + hi*4;

  short4v gA[2], gB[2], gC[2];
  gA[0] = *(const short4v*)gp0;           gA[1] = *(const short4v*)gp1;
  gB[0] = *(const short4v*)(gp0 + 65536); gB[1] = *(const short4v*)(gp1 + 65536);

  const int j0 = (w*8 + g2*2)*4 + hi;     // j for u=0; u=1 is j0+4
  const long hob = (long)(sb*4 + sq)*Ss*HID;

  int p = 0;
  __syncthreads();

  #pragma unroll 1
  for (int t=0; t<Ss; ++t){
    int t2 = (t+2 < Ss) ? (t+2) : t;
    gC[0] = *(const short4v*)(gp0 + t2*65536);
    gC[1] = *(const short4v*)(gp1 + t2*65536);

    LBAR();   // h_{t-1} writes visible; prefetch loads stay in flight

    long bfr[8];
    #pragma unroll
    for (int kf=0; kf<8; ++kf)
      bfr[kf] = *(const long*)&hq[p][sq][kf*32 + hi*8];

    int4v acc[8];
    #pragma unroll
    for (int ti=0; ti<8; ++ti){
      int4v a = {0,0,0,0};
      #pragma unroll
      for (int kf=0; kf<8; ++kf)
        a = __builtin_amdgcn_mfma_i32_16x16x32_i8(wfr[ti][kf], bfr[kf], a, 0,0,0);
      acc[ti] = a;
    }

    #pragma unroll
    for (int u=0; u<2; ++u){
      int4v x0 = sel4(g2 & 1, acc[2+u], acc[0+u]);
      int4v x1 = sel4(g2 & 1, acc[6+u], acc[4+u]);
      int4v aS = sel4(g2 & 2, x1, x0);
      float g0v = fmaf((float)aS[0], dmq[u][0], bf2f((ushort_t)gA[u][0]));
      float g1v = fmaf((float)aS[1], dmq[u][1], bf2f((ushort_t)gA[u][1]));
      float g2v = fmaf((float)aS[2], dmq[u][2], bf2f((ushort_t)gA[u][2]));
      float g3v = fmaf((float)aS[3], dmq[u][3], bf2f((ushort_t)gA[u][3]));
      float iv = fsig(g0v), fv = fsig(g1v), gg = ftanh(g2v), ov = fsig(g3v);
      float cn = fmaf(fv, cst[u], iv*gg);
      cst[u] = cn;
      float hn = ov * ftanh(cn);
      int j = j0 + u*4;
      hout[hob + (long)t*HID + j] = hn;
      hq[1-p][sq][j] = (signed char)__float2int_rn(hn * 127.0f);
    }

    gA[0]=gB[0]; gA[1]=gB[1]; gB[0]=gC[0]; gB[1]=gC[1];
    p ^= 1;
  }
}

// ---------------- emissions: emit = concat(h_fwd, h_bwd)*valid @ We^T + be
__global__ __launch_bounds__(128) void k_emit(const float* __restrict__ hfw, const float* __restrict__ hrw,
    const int* __restrict__ lengths, const float* __restrict__ We, const float* __restrict__ be,
    float* __restrict__ emit)
{
  __shared__ float Wl[NT*516];
  const int b = blockIdx.x, tg = blockIdx.y;
  const int tid = threadIdx.x;
  for (int i = tid; i < NT*512; i += 128)
    Wl[(i>>9)*516 + (i&511)] = We[i];
  __syncthreads();
  const int L = lengths[b];
  const int j = tid & 63;
  const int th = tid >> 6;
  float bej = (j<NT) ? be[j] : 0.f;
  for (int ttq=0; ttq<8; ttq++){
    int t = tg*16 + th*8 + ttq;
    int n = b*Ss + t;
    float acc = bej;
    if (j < NT && t < L){
      const float* hf_ = hfw + (long)n*HID;
      const float* hb_ = hrw + (long)(b*Ss + (L-1-t))*HID;
      const float* wr = Wl + j*516;
      for (int k=0;k<HID;k+=4){
        float4 hv = *(const float4*)(hf_+k);
        float4 wv = *(const float4*)(wr+k);
        acc += hv.x*wv.x + hv.y*wv.y + hv.z*wv.z + hv.w*wv.w;
      }
      for (int k=0;k<HID;k+=4){
        float4 hv = *(const float4*)(hb_+k);
        float4 wv = *(const float4*)(wr+256+k);
        acc += hv.x*wv.x + hv.y*wv.y + hv.z*wv.z + hv.w*wv.w;
      }
    }
    if (j < NT) emit[(long)n*NT + j] = acc;
  }
}

// ---------------- CRF: gold score + exp-domain forward algorithm; out = pred - gold
__global__ __launch_bounds__(64) void k_crf(const float* __restrict__ emit, const int* __restrict__ tags,
    const int* __restrict__ lengths, const float* __restrict__ trans, float* __restrict__ out)
{
  const int b = blockIdx.x;
  const int tid = threadIdx.x;
  __shared__ float Tl[NT*NT];
  __shared__ float A[NT];
  __shared__ float red[64];
  for (int i=tid;i<NT*NT;i+=64) Tl[i] = trans[i];
  __syncthreads();
  const int L = lengths[b];

  float gp = 0.f;
  for (int t=tid; t<L; t+=64){
    int tg = tags[b*Ss+t];
    gp += emit[(long)(b*Ss+t)*NT + tg];
    if (t>=1) gp += Tl[tags[b*Ss+t-1]*NT + tg];
  }
  red[tid] = gp; __syncthreads();
  for (int off=32; off; off>>=1){ if (tid<off) red[tid]+=red[tid+off]; __syncthreads(); }
  float gold = red[0];

  const int j = tid;
  float Ereg[NT];
  if (j < NT){
    #pragma unroll
    for (int i=0;i<NT;i++) Ereg[i] = __expf(Tl[i*NT + j]);
  }
  float a0 = (j<NT) ? emit[(long)(b*Ss)*NT + j] : -1e30f;
  float m = a0;
  #pragma unroll
  for (int off=1; off<64; off<<=1) m = fmaxf(m, __shfl_xor(m, off));
  float logZ = m;
  if (j<NT) A[j] = __expf(a0 - m);
  __syncthreads();

  for (int t=1;t<L;t++){
    float v = 0.f;
    if (j<NT){
      #pragma unroll
      for (int i=0;i<NT;i++) v = fmaf(A[i], Ereg[i], v);
      v *= __expf(emit[(long)(b*Ss+t)*NT + j]);
    }
    float mm = (j<NT) ? v : 0.f;
    #pragma unroll
    for (int off=1; off<64; off<<=1) mm = fmaxf(mm, __shfl_xor(mm, off));
    logZ += __logf(mm);
    float vn = v / mm;
    __syncthreads();
    if (j<NT) A[j] = vn;
    __syncthreads();
  }
  float s = (j<NT) ? A[j] : 0.f;
  #pragma unroll
  for (int off=1; off<64; off<<=1) s += __shfl_xor(s, off);
  float pred = logZ + __logf(s);
  if (tid==0) out[b] = pred - gold;
}

extern "C" void kernel_launch(void* const* d_in, const int* in_sizes, int n_in,
                              void* d_out, int out_size, void* d_ws, size_t ws_size,
                              hipStream_t stream){
  const int*   sentences = (const int*)d_in[0];
  const int*   lengths   = (const int*)d_in[1];
  const int*   words     = (const int*)d_in[2];
  const int*   tags      = (const int*)d_in[3];
  const float* char_emb  = (const float*)d_in[4];
  const float* cWi_f = (const float*)d_in[5];
  const float* cWh_f = (const float*)d_in[6];
  const float* cb_f  = (const float*)d_in[7];
  const float* cWi_b = (const float*)d_in[8];
  const float* cWh_b = (const float*)d_in[9];
  const float* cb_b  = (const float*)d_in[10];
  const float* word_emb = (const float*)d_in[11];
  const float* wWi_f = (const float*)d_in[12];
  const float* wWh_f = (const float*)d_in[13];
  const float* wb_f  = (const float*)d_in[14];
  const float* wWi_b = (const float*)d_in[15];
  const float* wWh_b = (const float*)d_in[16];
  const float* wb_b  = (const float*)d_in[17];
  const float* We   = (const float*)d_in[18];
  const float* be   = (const float*)d_in[19];
  const float* trans= (const float*)d_in[20];
  float* out = (float*)d_out;

  float* ws = (float*)d_ws;
  float* hf   = ws;                               // 819200 f32
  float* hb   = hf  + 819200;                     // 819200 f32
  float* hfw  = hb  + 819200;                     // 2097152 f32
  float* hrw  = hfw + 2097152;                    // 2097152 f32
  float* emit = hrw + 2097152;                    // 409600 f32
  float* dm   = emit + 409600;                    // 2048 f32
  ushort_t* xbf = (ushort_t*)(dm + 2048);         // 8192*416 bf16
  ushort_t* wiP = xbf + 3407872;                  // 2*1024*416 bf16
  ushort_t* gwF = wiP + 851968;                   // 8388608 bf16
  ushort_t* gwB = gwF + 8388608;                  // 8388608 bf16
  ushort_t* P   = gwB + 8388608;                  // 16777216 bf16
  signed char* whq = (signed char*)(P + 16777216);// 524288 i8

  k_cvt_whq<<<dim3(512), 256, 0, stream>>>(wWh_f, wWh_b, whq, dm);
  k_cvt_wi<<<dim3(3333), 256, 0, stream>>>(wWi_f, wWi_b, wiP);
  k_char_mfma<<<dim3(256,2), 256, 0, stream>>>(words, char_emb,
      cWi_f, cWh_f, cb_f, hf,
      cWi_b, cWh_b, cb_b, hb);
  k_build_x<<<dim3(13312), 256, 0, stream>>>(sentences, word_emb, hf, hb, xbf);
  k_gemm_mfma<<<dim3(64,8,2), 256, 0, stream>>>(xbf, lengths, wiP, wb_f, wb_b, gwF, gwB);
  k_gw_pack<<<dim3(65536), 256, 0, stream>>>(gwF, gwB, P);
  k_word_i8<<<dim3(16,2), 512, 0, stream>>>(whq, dm, P, hfw, hrw);
  k_emit<<<dim3(64,8), 128, 0, stream>>>(hfw, hrw, lengths, We, be, emit);
  k_crf<<<dim3(64), 64, 0, stream>>>(emit, tags, lengths, trans, out);
}

// Round 5
// 465.192 us; speedup vs baseline: 6.2942x; 1.1739x over previous
//
#include <hip/hip_runtime.h>
#include <math.h>

#define Bb 64
#define Ss 128
#define BS 8192
#define Ww 16
#define CE 50
#define CH 100
#define EMBD 300
#define HID 256
#define WG 1024
#define XD 400
#define XDP 416
#define NT 50

typedef unsigned short ushort_t;
typedef unsigned int uint_t;
using bf16x8 = __attribute__((ext_vector_type(8))) short;
using short8v = __attribute__((ext_vector_type(8))) short;
using short4v = __attribute__((ext_vector_type(4))) short;
using f32x4  = __attribute__((ext_vector_type(4))) float;
using int4v  = __attribute__((ext_vector_type(4))) int;

#define LBAR() do { asm volatile("s_waitcnt lgkmcnt(0)" ::: "memory"); __builtin_amdgcn_s_barrier(); } while(0)

__device__ __forceinline__ float sigf(float x){ return 1.0f/(1.0f+__expf(-x)); }
__device__ __forceinline__ float tanhfast(float x){
  float e = __expf(-2.0f*fabsf(x));
  float r = (1.0f-e)/(1.0f+e);
  return copysignf(r,x);
}
__device__ __forceinline__ float fsig(float x){
  float e = __builtin_amdgcn_exp2f(-1.4426950408889634f * x);
  return __builtin_amdgcn_rcpf(1.0f + e);
}
__device__ __forceinline__ float ftanh(float x){
  float e = __builtin_amdgcn_exp2f(-2.8853900817779268f * fabsf(x));
  float r = 1.0f - 2.0f*e*__builtin_amdgcn_rcpf(1.0f + e);
  return copysignf(r, x);
}
__device__ __forceinline__ ushort_t f2bf(float f){
  uint_t u = __float_as_uint(f);
  uint_t r = (u + 0x7fffu + ((u>>16)&1u)) >> 16;
  return (ushort_t)r;
}
__device__ __forceinline__ float bf2f(ushort_t u){ return __uint_as_float(((uint_t)u)<<16); }

__device__ __forceinline__ int4v sel4(int c, int4v a, int4v b){
  int4v r;
  #pragma unroll
  for (int i=0;i<4;i++) r[i] = c ? a[i] : b[i];
  return r;
}

// ---------------- Wh f32 -> row-scaled int8, gates-on-M layout: Whq[dir][m=j*4+g][k]
__global__ __launch_bounds__(256) void k_cvt_whq(const float* __restrict__ whf, const float* __restrict__ whb,
                                                 signed char* __restrict__ q, float* __restrict__ dm){
  const int tid = threadIdx.x;
  const int lane = tid & 63, w = tid >> 6;
  const int gm = blockIdx.x*4 + w;          // 0..2047
  const int dir = gm >> 10, m = gm & 1023;
  const float* src = dir ? whb : whf;
  const float* row = src + (long)((m&3)*HID + (m>>2)) * HID;
  float4 v = *(const float4*)&row[lane*4];
  float mx = fmaxf(fmaxf(fabsf(v.x), fabsf(v.y)), fmaxf(fabsf(v.z), fabsf(v.w)));
  #pragma unroll
  for (int off=32; off; off>>=1) mx = fmaxf(mx, __shfl_xor(mx, off));
  float s = (mx > 0.f) ? (127.0f / mx) : 0.f;
  int b0 = __float2int_rn(v.x*s) & 255;
  int b1 = __float2int_rn(v.y*s) & 255;
  int b2 = __float2int_rn(v.z*s) & 255;
  int b3 = __float2int_rn(v.w*s) & 255;
  uint_t pk = (uint_t)b0 | ((uint_t)b1<<8) | ((uint_t)b2<<16) | ((uint_t)b3<<24);
  *(uint_t*)&q[(long)gm*HID + lane*4] = pk;
  if (lane == 0) dm[gm] = mx * (1.0f/16129.0f);   // 127*127
}

// ---------------- char BiLSTM via MFMA (unchanged, verified round 2)
__global__ __launch_bounds__(256, 2) void k_char_mfma(const int* __restrict__ words, const float* __restrict__ cemb,
    const float* __restrict__ cWiF, const float* __restrict__ cWhF, const float* __restrict__ cbF, float* __restrict__ hfo,
    const float* __restrict__ cWiB, const float* __restrict__ cWhB, const float* __restrict__ cbB, float* __restrict__ hbo)
{
  const int rev = blockIdx.y;
  const float* cWi = rev ? cWiB : cWiF;
  const float* cWh = rev ? cWhB : cWhF;
  const float* cb  = rev ? cbB  : cbF;
  float* hout = rev ? hbo : hfo;
  const int n0 = blockIdx.x * 32;
  const int tid = threadIdx.x;
  const int lane = tid & 63;
  const int w = tid >> 6;

  __shared__ ushort_t xh[32][200];
  __shared__ ushort_t wi_l[400][72];
  __shared__ float    bias_l[400];
  __shared__ int      wbuf[32][Ww];

  for (int i = tid; i < 32*Ww; i += 256)
    wbuf[i>>4][i&15] = words[(n0 + (i>>4))*Ww + (i&15)];
  for (int i = tid; i < 3200; i += 256) ((uint_t*)xh)[i] = 0u;
  for (int r = tid; r < 400; r += 256){
    int j = r >> 2, g = r & 3;
    const float* src = cWi + (g*CH + j)*CE;
    for (int k = 0; k < 72; ++k)
      wi_l[r][k] = (k < CE) ? f2bf(src[k]) : (ushort_t)0;
    bias_l[r] = cb[g*CH + j];
  }

  bf16x8 whr[7][4];
  #pragma unroll
  for (int ti=0; ti<7; ++ti){
    int tm = w + ti*4;
    #pragma unroll
    for (int kk=0; kk<4; ++kk){
      bf16x8 v;
      #pragma unroll
      for (int e=0;e<8;++e) v[e]=0;
      if (tm < 25){
        int m = tm*16 + (lane & 15);
        int j = m >> 2, g = m & 3;
        const float* src = cWh + (g*CH + j)*CH;
        int kh0 = kk*32 + ((lane>>4)<<3);
        #pragma unroll
        for (int e=0;e<8;++e){
          int kh = kh0 + e;
          if (kh < CH) v[e] = (short)f2bf(src[kh]);
        }
      }
      whr[ti][kk] = v;
    }
  }

  float cst[7][2], hreg[7][2];
  #pragma unroll
  for (int ti=0; ti<7; ++ti){ cst[ti][0]=0.f; cst[ti][1]=0.f; hreg[ti][0]=0.f; hreg[ti][1]=0.f; }

  const int ps = tid >> 3;
  const int pk = (tid & 7) * 8;
  float xv[8];

  __syncthreads();

  {
    int tt = rev ? (Ww-1) : 0;
    int wd = wbuf[ps][tt];
    const float* src = cemb + wd*CE + pk;
    #pragma unroll
    for (int e=0;e<8;++e){ int k = pk+e; xv[e] = (k < CE) ? src[e] : 0.f; }
  }

  #pragma unroll 1
  for (int t=0; t<Ww; ++t){
    __syncthreads();
    if (t){
      #pragma unroll
      for (int ti=0; ti<7; ++ti){
        int tm = w + ti*4;
        if (tm < 25){
          int j = tm*4 + (lane>>4);
          #pragma unroll
          for (int nt=0; nt<2; ++nt){
            int s = nt*16 + (lane & 15);
            xh[s][64 + j] = f2bf(hreg[ti][nt]);
          }
        }
      }
    }
    {
      bf16x8 pxv;
      #pragma unroll
      for (int e=0;e<8;++e) pxv[e] = (short)f2bf(xv[e]);
      *((bf16x8*)&xh[ps][pk]) = pxv;
    }
    if (t+1 < Ww){
      int tt2 = rev ? (Ww-2-t) : (t+1);
      int wd = wbuf[ps][tt2];
      const float* src = cemb + wd*CE + pk;
      #pragma unroll
      for (int e=0;e<8;++e){ int k = pk+e; xv[e] = (k < CE) ? src[e] : 0.f; }
    }
    __syncthreads();

    bf16x8 bf[2][6];
    #pragma unroll
    for (int nt=0; nt<2; ++nt){
      int s = nt*16 + (lane & 15);
      #pragma unroll
      for (int kk=0; kk<6; ++kk){
        int k = kk*32 + ((lane>>4)<<3);
        bf[nt][kk] = *((const bf16x8*)&xh[s][k]);
      }
    }
    #pragma unroll
    for (int ti=0; ti<7; ++ti){
      int tm = w + ti*4;
      if (tm < 25){
        int row = tm*16 + (lane & 15);
        int kb = (lane>>4)<<3;
        bf16x8 awi0 = *((const bf16x8*)&wi_l[row][kb]);
        bf16x8 awi1 = *((const bf16x8*)&wi_l[row][32+kb]);
        f32x4 bias_v = *((const f32x4*)&bias_l[tm*16 + ((lane>>4)<<2)]);
        #pragma unroll
        for (int nt=0; nt<2; ++nt){
          f32x4 acc = bias_v;
          acc = __builtin_amdgcn_mfma_f32_16x16x32_bf16(awi0, bf[nt][0], acc, 0,0,0);
          acc = __builtin_amdgcn_mfma_f32_16x16x32_bf16(awi1, bf[nt][1], acc, 0,0,0);
          #pragma unroll
          for (int kk=0; kk<4; ++kk)
            acc = __builtin_amdgcn_mfma_f32_16x16x32_bf16(whr[ti][kk], bf[nt][2+kk], acc, 0,0,0);
          float iv = sigf(acc[0]), fv = sigf(acc[1]);
          float gv = tanhfast(acc[2]), ov = sigf(acc[3]);
          float cn = fmaf(fv, cst[ti][nt], iv*gv);
          cst[ti][nt] = cn;
          hreg[ti][nt] = ov * tanhfast(cn);
        }
      }
    }
  }

  #pragma unroll
  for (int ti=0; ti<7; ++ti){
    int tm = w + ti*4;
    if (tm < 25){
      int j = tm*4 + (lane>>4);
      #pragma unroll
      for (int nt=0; nt<2; ++nt){
        int s = nt*16 + (lane & 15);
        hout[(n0 + s)*CH + j] = hreg[ti][nt];
      }
    }
  }
}

// ---------------- xbf = [word_emb gather | hf+hb | 0-pad], bf16 [8192][416]
__global__ void k_build_x(const int* __restrict__ sent, const float* __restrict__ wemb,
                          const float* __restrict__ hf, const float* __restrict__ hb,
                          ushort_t* __restrict__ xbf){
  long i = (long)blockIdx.x*256 + threadIdx.x;
  if (i >= (long)BS*XDP) return;
  int n = (int)(i / XDP), e = (int)(i - (long)n*XDP);
  float v = 0.f;
  if (e < EMBD) v = wemb[(long)sent[n]*EMBD + e];
  else if (e < XD) { int jj = e-EMBD; v = hf[n*CH+jj] + hb[n*CH+jj]; }
  xbf[i] = f2bf(v);
}

// ---------------- Wi f32 -> bf16 padded: wiP[dir][1024][416]
__global__ void k_cvt_wi(const float* __restrict__ wiF, const float* __restrict__ wiB,
                         ushort_t* __restrict__ wiP){
  int i = blockIdx.x*256 + threadIdx.x;
  if (i >= 2*WG*XDP) return;
  int dir = i >= WG*XDP;
  int ii = dir ? i - WG*XDP : i;
  int n = ii / XDP, k = ii - n*XDP;
  const float* src = dir ? wiB : wiF;
  wiP[i] = (k < XD) ? f2bf(src[n*XD + k]) : (ushort_t)0;
}

// ---------------- word input-gate GEMM via bf16 MFMA; writes P layout directly.
// P[dir][t][sb][sl][m'=j*4+g]
__global__ __launch_bounds__(256) void k_gemm_mfma(const ushort_t* __restrict__ xbf, const int* __restrict__ lengths,
    const ushort_t* __restrict__ wiP, const float* __restrict__ wbF, const float* __restrict__ wbB,
    ushort_t* __restrict__ P)
{
  const int rev = blockIdx.z;
  const int b = blockIdx.x;
  const int n0 = blockIdx.y * 128;
  const float* bias = rev ? wbB : wbF;
  const int m0 = b*Ss;
  const int L = lengths[b];

  __shared__ ushort_t As[128*32];
  __shared__ ushort_t Bs[128*32];
  __shared__ float bl[128];

  const int tid = threadIdx.x;
  const int lane = tid & 63, w = tid >> 6;
  const int lo = lane & 15, hi = lane >> 4;
  const int wm0 = (w>>1)*64, wn0 = (w&1)*64;

  if (tid < 128) bl[tid] = bias[n0 + tid];

  long abase[2], bbase[2];
  #pragma unroll
  for (int u=0; u<2; ++u){
    int cid = u*256 + tid;
    int r = cid >> 2, kc = (cid & 3)*8;
    int srow;
    if (!rev) srow = m0 + r;
    else { int rr = L-1-r; srow = m0 + (rr < 0 ? 0 : rr); }
    abase[u] = (long)srow*XDP + kc;
    bbase[u] = ((long)rev*WG + n0 + r)*XDP + kc;
  }

  f32x4 acc[4][4];
  #pragma unroll
  for (int i=0;i<4;i++)
    #pragma unroll
    for (int q=0;q<4;q++){ acc[i][q][0]=0.f; acc[i][q][1]=0.f; acc[i][q][2]=0.f; acc[i][q][3]=0.f; }

  bf16x8 avn[2], bvn[2];
  #pragma unroll
  for (int u=0; u<2; ++u){
    avn[u] = *(const bf16x8*)&xbf[abase[u]];
    bvn[u] = *(const bf16x8*)&wiP[bbase[u]];
  }

  #pragma unroll 1
  for (int kt=0; kt<13; ++kt){
    bf16x8 av[2], bv[2];
    #pragma unroll
    for (int u=0; u<2; ++u){ av[u]=avn[u]; bv[u]=bvn[u]; }
    if (kt < 12){
      int k0 = (kt+1)*32;
      #pragma unroll
      for (int u=0; u<2; ++u){
        avn[u] = *(const bf16x8*)&xbf[abase[u] + k0];
        bvn[u] = *(const bf16x8*)&wiP[bbase[u] + k0];
      }
    }
    LBAR();   // all frag reads of previous tile done
    #pragma unroll
    for (int u=0; u<2; ++u){
      *(bf16x8*)&As[(u*256 + tid)*8] = av[u];
      *(bf16x8*)&Bs[(u*256 + tid)*8] = bv[u];
    }
    LBAR();   // writes visible
    bf16x8 af[4], bfr[4];
    #pragma unroll
    for (int mt=0; mt<4; ++mt) af[mt] = *(const bf16x8*)&As[(wm0 + mt*16 + lo)*32 + hi*8];
    #pragma unroll
    for (int nt=0; nt<4; ++nt) bfr[nt] = *(const bf16x8*)&Bs[(wn0 + nt*16 + lo)*32 + hi*8];
    #pragma unroll
    for (int mt=0; mt<4; ++mt)
      #pragma unroll
      for (int nt=0; nt<4; ++nt)
        acc[mt][nt] = __builtin_amdgcn_mfma_f32_16x16x32_bf16(af[mt], bfr[nt], acc[mt][nt], 0,0,0);
  }

  LBAR();
  #pragma unroll
  for (int nt=0; nt<4; ++nt){
    int n = n0 + wn0 + nt*16 + lo;            // gate-major col = g*256 + j
    float bn = bl[wn0 + nt*16 + lo];
    int mp = (n & 255)*4 + (n >> 8);          // m' = j*4 + g
    #pragma unroll
    for (int mt=0; mt<4; ++mt){
      #pragma unroll
      for (int r=0; r<4; ++r){
        int t = wm0 + mt*16 + hi*4 + r;       // 0..127
        long pidx = ((((long)rev*Ss + t)*16 + (b>>2))*4 + (b&3))*1024 + mp;
        P[pidx] = f2bf(acc[mt][nt][r] + bn);
      }
    }
  }
}

// ---------------- word LSTM recurrence via int8 MFMA K=64; Wh resident in registers.
// Grid: (16 sb, 2 dir), 512 threads (8 waves). Wave w owns M-tiles w*8..w*8+7.
// Lane (hi=lane>>4, lo=lane&15): sq=lo&3 (seq), g2=lo>>2 selects the lane's 2 owned tiles.
__global__ __launch_bounds__(512, 2) void k_word_i8(
    const signed char* __restrict__ whq, const float* __restrict__ dmg,
    const ushort_t* __restrict__ P, float* __restrict__ hfw, float* __restrict__ hrw)
{
  const int dir = blockIdx.y, sb = blockIdx.x;
  const int tid = threadIdx.x, lane = tid & 63, w = tid >> 6;
  float* hout = dir ? hrw : hfw;

  __shared__ signed char hq[2][4][320];      // stride 320 -> 2-way bank aliasing (free)
  if (tid < 320) ((int*)hq)[tid] = 0;        // zero hq[0]

  const int hi = lane >> 4;
  const int lo = lane & 15;
  const int sq = lo & 3;
  const int g2 = lo >> 2;

  int4v wfr[8][4];
  #pragma unroll
  for (int ti=0; ti<8; ++ti){
    int mA = (w*8+ti)*16 + lo;
    #pragma unroll
    for (int kf=0; kf<4; ++kf)
      wfr[ti][kf] = *(const int4v*)&whq[(dir*1024 + mA)*HID + kf*64 + hi*16];
  }
  f32x4 dmq[2];
  #pragma unroll
  for (int u=0; u<2; ++u)
    dmq[u] = *(const f32x4*)&dmg[dir*1024 + (w*8 + g2*2+u)*16 + hi*4];

  float cst[2] = {0.f, 0.f};

  const ushort_t* Pd = P + (long)dir*8388608 + (sb*4 + sq)*1024;
  const ushort_t* gp0 = Pd + (w*8 + g2*2+0)*16 + hi*4;
  const ushort_t* gp1 = Pd + (w*8 + g2*2+1)*16 + hi*4;

  short4v gA[2], gB[2], gC[2];
  gA[0] = *(const short4v*)gp0;           gA[1] = *(const short4v*)gp1;
  gB[0] = *(const short4v*)(gp0 + 65536); gB[1] = *(const short4v*)(gp1 + 65536);

  const int j0 = (w*8 + g2*2)*4 + hi;     // j for u=0; u=1 is j0+4
  const long hob = (long)(sb*4 + sq)*Ss*HID;

  int p = 0;
  __syncthreads();

  #pragma unroll 1
  for (int t=0; t<Ss; ++t){
    int t2 = (t+2 < Ss) ? (t+2) : t;
    gC[0] = *(const short4v*)(gp0 + t2*65536);
    gC[1] = *(const short4v*)(gp1 + t2*65536);

    LBAR();   // h_{t-1} writes visible; global prefetch stays in flight

    int4v bfr[4];
    #pragma unroll
    for (int kf=0; kf<4; ++kf)
      bfr[kf] = *(const int4v*)&hq[p][sq][kf*64 + hi*16];

    __builtin_amdgcn_s_setprio(1);
    int4v acc[8];
    #pragma unroll
    for (int ti=0; ti<8; ++ti){
      int4v a = {0,0,0,0};
      #pragma unroll
      for (int kf=0; kf<4; ++kf)
        a = __builtin_amdgcn_mfma_i32_16x16x64_i8(wfr[ti][kf], bfr[kf], a, 0,0,0);
      acc[ti] = a;
    }
    __builtin_amdgcn_s_setprio(0);

    #pragma unroll
    for (int u=0; u<2; ++u){
      int4v x0 = sel4(g2 & 1, acc[2+u], acc[0+u]);
      int4v x1 = sel4(g2 & 1, acc[6+u], acc[4+u]);
      int4v aS = sel4(g2 & 2, x1, x0);
      float g0v = fmaf((float)aS[0], dmq[u][0], bf2f((ushort_t)gA[u][0]));
      float g1v = fmaf((float)aS[1], dmq[u][1], bf2f((ushort_t)gA[u][1]));
      float g2v = fmaf((float)aS[2], dmq[u][2], bf2f((ushort_t)gA[u][2]));
      float g3v = fmaf((float)aS[3], dmq[u][3], bf2f((ushort_t)gA[u][3]));
      float iv = fsig(g0v), fv = fsig(g1v), gg = ftanh(g2v), ov = fsig(g3v);
      float cn = fmaf(fv, cst[u], iv*gg);
      cst[u] = cn;
      float hn = ov * ftanh(cn);
      int j = j0 + u*4;
      hout[hob + (long)t*HID + j] = hn;
      hq[1-p][sq][j] = (signed char)__float2int_rn(hn * 127.0f);
    }

    gA[0]=gB[0]; gA[1]=gB[1]; gB[0]=gC[0]; gB[1]=gC[1];
    p ^= 1;
  }
}

// ---------------- emissions: emit = concat(h_fwd, h_bwd)*valid @ We^T + be
__global__ __launch_bounds__(128) void k_emit(const float* __restrict__ hfw, const float* __restrict__ hrw,
    const int* __restrict__ lengths, const float* __restrict__ We, const float* __restrict__ be,
    float* __restrict__ emit)
{
  __shared__ float Wl[NT*516];
  const int b = blockIdx.x, tg = blockIdx.y;
  const int tid = threadIdx.x;
  for (int i = tid; i < NT*512; i += 128)
    Wl[(i>>9)*516 + (i&511)] = We[i];
  __syncthreads();
  const int L = lengths[b];
  const int j = tid & 63;
  const int th = tid >> 6;
  float bej = (j<NT) ? be[j] : 0.f;
  for (int ttq=0; ttq<8; ttq++){
    int t = tg*16 + th*8 + ttq;
    int n = b*Ss + t;
    float acc = bej;
    if (j < NT && t < L){
      const float* hf_ = hfw + (long)n*HID;
      const float* hb_ = hrw + (long)(b*Ss + (L-1-t))*HID;
      const float* wr = Wl + j*516;
      for (int k=0;k<HID;k+=4){
        float4 hv = *(const float4*)(hf_+k);
        float4 wv = *(const float4*)(wr+k);
        acc += hv.x*wv.x + hv.y*wv.y + hv.z*wv.z + hv.w*wv.w;
      }
      for (int k=0;k<HID;k+=4){
        float4 hv = *(const float4*)(hb_+k);
        float4 wv = *(const float4*)(wr+256+k);
        acc += hv.x*wv.x + hv.y*wv.y + hv.z*wv.z + hv.w*wv.w;
      }
    }
    if (j < NT) emit[(long)n*NT + j] = acc;
  }
}

// ---------------- CRF: gold score + exp-domain forward algorithm; out = pred - gold
__global__ __launch_bounds__(64) void k_crf(const float* __restrict__ emit, const int* __restrict__ tags,
    const int* __restrict__ lengths, const float* __restrict__ trans, float* __restrict__ out)
{
  const int b = blockIdx.x;
  const int tid = threadIdx.x;
  __shared__ float Tl[NT*NT];
  __shared__ float A[NT];
  __shared__ float red[64];
  for (int i=tid;i<NT*NT;i+=64) Tl[i] = trans[i];
  __syncthreads();
  const int L = lengths[b];

  float gp = 0.f;
  for (int t=tid; t<L; t+=64){
    int tg = tags[b*Ss+t];
    gp += emit[(long)(b*Ss+t)*NT + tg];
    if (t>=1) gp += Tl[tags[b*Ss+t-1]*NT + tg];
  }
  red[tid] = gp; __syncthreads();
  for (int off=32; off; off>>=1){ if (tid<off) red[tid]+=red[tid+off]; __syncthreads(); }
  float gold = red[0];

  const int j = tid;
  float Ereg[NT];
  if (j < NT){
    #pragma unroll
    for (int i=0;i<NT;i++) Ereg[i] = __expf(Tl[i*NT + j]);
  }
  float a0 = (j<NT) ? emit[(long)(b*Ss)*NT + j] : -1e30f;
  float m = a0;
  #pragma unroll
  for (int off=1; off<64; off<<=1) m = fmaxf(m, __shfl_xor(m, off));
  float logZ = m;
  if (j<NT) A[j] = __expf(a0 - m);
  __syncthreads();

  for (int t=1;t<L;t++){
    float v = 0.f;
    if (j<NT){
      #pragma unroll
      for (int i=0;i<NT;i++) v = fmaf(A[i], Ereg[i], v);
      v *= __expf(emit[(long)(b*Ss+t)*NT + j]);
    }
    float mm = (j<NT) ? v : 0.f;
    #pragma unroll
    for (int off=1; off<64; off<<=1) mm = fmaxf(mm, __shfl_xor(mm, off));
    logZ += __logf(mm);
    float vn = v / mm;
    __syncthreads();
    if (j<NT) A[j] = vn;
    __syncthreads();
  }
  float s = (j<NT) ? A[j] : 0.f;
  #pragma unroll
  for (int off=1; off<64; off<<=1) s += __shfl_xor(s, off);
  float pred = logZ + __logf(s);
  if (tid==0) out[b] = pred - gold;
}

extern "C" void kernel_launch(void* const* d_in, const int* in_sizes, int n_in,
                              void* d_out, int out_size, void* d_ws, size_t ws_size,
                              hipStream_t stream){
  const int*   sentences = (const int*)d_in[0];
  const int*   lengths   = (const int*)d_in[1];
  const int*   words     = (const int*)d_in[2];
  const int*   tags      = (const int*)d_in[3];
  const float* char_emb  = (const float*)d_in[4];
  const float* cWi_f = (const float*)d_in[5];
  const float* cWh_f = (const float*)d_in[6];
  const float* cb_f  = (const float*)d_in[7];
  const float* cWi_b = (const float*)d_in[8];
  const float* cWh_b = (const float*)d_in[9];
  const float* cb_b  = (const float*)d_in[10];
  const float* word_emb = (const float*)d_in[11];
  const float* wWi_f = (const float*)d_in[12];
  const float* wWh_f = (const float*)d_in[13];
  const float* wb_f  = (const float*)d_in[14];
  const float* wWi_b = (const float*)d_in[15];
  const float* wWh_b = (const float*)d_in[16];
  const float* wb_b  = (const float*)d_in[17];
  const float* We   = (const float*)d_in[18];
  const float* be   = (const float*)d_in[19];
  const float* trans= (const float*)d_in[20];
  float* out = (float*)d_out;

  float* ws = (float*)d_ws;
  float* hf   = ws;                               // 819200 f32
  float* hb   = hf  + 819200;                     // 819200 f32
  float* hfw  = hb  + 819200;                     // 2097152 f32
  float* hrw  = hfw + 2097152;                    // 2097152 f32
  float* emit = hrw + 2097152;                    // 409600 f32
  float* dm   = emit + 409600;                    // 2048 f32
  ushort_t* xbf = (ushort_t*)(dm + 2048);         // 8192*416 bf16
  ushort_t* wiP = xbf + 3407872;                  // 2*1024*416 bf16
  ushort_t* P   = wiP + 851968;                   // 16777216 bf16
  signed char* whq = (signed char*)(P + 16777216);// 524288 i8

  k_cvt_whq<<<dim3(512), 256, 0, stream>>>(wWh_f, wWh_b, whq, dm);
  k_cvt_wi<<<dim3(3333), 256, 0, stream>>>(wWi_f, wWi_b, wiP);
  k_char_mfma<<<dim3(256,2), 256, 0, stream>>>(words, char_emb,
      cWi_f, cWh_f, cb_f, hf,
      cWi_b, cWh_b, cb_b, hb);
  k_build_x<<<dim3(13312), 256, 0, stream>>>(sentences, word_emb, hf, hb, xbf);
  k_gemm_mfma<<<dim3(64,8,2), 256, 0, stream>>>(xbf, lengths, wiP, wb_f, wb_b, P);
  k_word_i8<<<dim3(16,2), 512, 0, stream>>>(whq, dm, P, hfw, hrw);
  k_emit<<<dim3(64,8), 128, 0, stream>>>(hfw, hrw, lengths, We, be, emit);
  k_crf<<<dim3(64), 64, 0, stream>>>(emit, tags, lengths, trans, out);
}